// Round 1
// 1111.809 us; speedup vs baseline: 1.3977x; 1.3977x over previous
//
#include <hip/hip_runtime.h>
#include <math.h>

#define NPAD 65

// ---------- small device helpers ----------
__device__ __forceinline__ float leaky(float x) { return x > 0.f ? x : 0.01f * x; }
__device__ __forceinline__ float eluf(float x)  { return x > 0.f ? x : (__expf(x) - 1.f); }
__device__ __forceinline__ float sigm(float x)  { return 1.f / (1.f + __expf(-x)); }
__device__ __forceinline__ float tanhfast(float x) { return 1.f - 2.f / (__expf(2.f * x) + 1.f); }

__device__ __forceinline__ float bcastf(float v, int k) {
    return __uint_as_float((unsigned)__builtin_amdgcn_readlane((int)__float_as_uint(v), k));
}
__device__ __forceinline__ int bcasti(int v, int k) {
    return __builtin_amdgcn_readlane(v, k);
}
__device__ __forceinline__ float wredsum(float v) {
    #pragma unroll
    for (int off = 32; off; off >>= 1) v += __shfl_xor(v, off);
    return v;
}
__device__ __forceinline__ float wredmax(float v) {
    #pragma unroll
    for (int off = 32; off; off >>= 1) v = fmaxf(v, __shfl_xor(v, off));
    return v;
}

// ================= CSR build =================
__global__ __launch_bounds__(256) void k_hist(const int* __restrict__ ei, int* __restrict__ deg, int E_) {
    int e = blockIdx.x * 256 + threadIdx.x;
    if (e < E_) atomicAdd(&deg[ei[E_ + e]], 1);
}

__global__ __launch_bounds__(256) void k_scan1(const int* __restrict__ deg, int* __restrict__ bsum, int N_) {
    __shared__ int s[256];
    int i = blockIdx.x * 256 + threadIdx.x;
    s[threadIdx.x] = (i < N_) ? deg[i] : 0;
    __syncthreads();
    for (int off = 128; off; off >>= 1) {
        if (threadIdx.x < off) s[threadIdx.x] += s[threadIdx.x + off];
        __syncthreads();
    }
    if (threadIdx.x == 0) bsum[blockIdx.x] = s[0];
}

// parallel exclusive scan of block sums (single block, chunked w/ carry)
__global__ __launch_bounds__(512) void k_scan2(int* __restrict__ bsum, int nb) {
    __shared__ int s[512];
    __shared__ int carry_s;
    if (threadIdx.x == 0) carry_s = 0;
    __syncthreads();
    for (int base = 0; base < nb; base += 512) {
        int t = threadIdx.x;
        int idx = base + t;
        int v = (idx < nb) ? bsum[idx] : 0;
        s[t] = v;
        __syncthreads();
        #pragma unroll
        for (int off = 1; off < 512; off <<= 1) {
            int u = (t >= off) ? s[t - off] : 0;
            __syncthreads();
            s[t] += u;
            __syncthreads();
        }
        int carry = carry_s;
        if (idx < nb) bsum[idx] = carry + s[t] - v;   // exclusive
        __syncthreads();
        if (t == 0) carry_s = carry + s[511];
        __syncthreads();
    }
}

__global__ __launch_bounds__(256) void k_scan3(const int* __restrict__ deg, const int* __restrict__ bsum,
                                               int* __restrict__ row, int* __restrict__ cur, int N_, int E_) {
    __shared__ int s[256];
    int i = blockIdx.x * 256 + threadIdx.x;
    int d = (i < N_) ? deg[i] : 0;
    s[threadIdx.x] = d;
    __syncthreads();
    for (int off = 1; off < 256; off <<= 1) {
        int v = (threadIdx.x >= off) ? s[threadIdx.x - off] : 0;
        __syncthreads();
        s[threadIdx.x] += v;
        __syncthreads();
    }
    if (i < N_) {
        int ex = bsum[blockIdx.x] + s[threadIdx.x] - d;
        row[i] = ex; cur[i] = ex;
    }
    if (i == N_ - 1) row[N_] = E_;
}

__global__ __launch_bounds__(256) void k_scatter(const int* __restrict__ ei, int* __restrict__ cur,
                                                 int* __restrict__ csrc, int* __restrict__ ceid, int E_) {
    int e = blockIdx.x * 256 + threadIdx.x;
    if (e >= E_) return;
    int dst = ei[E_ + e];
    int slot = atomicAdd(&cur[dst], 1);
    csrc[slot] = ei[e];
    ceid[slot] = e;
}

__global__ __launch_bounds__(256) void k_gbounds(const int* __restrict__ batch, int* __restrict__ gst,
                                                 int N_, int G_) {
    int i = blockIdx.x * 256 + threadIdx.x;
    if (i >= N_) return;
    int b = batch[i];
    int prev = (i == 0) ? -1 : batch[i - 1];
    for (int g = prev + 1; g <= b; ++g) gst[g] = i;
    if (i == N_ - 1) { for (int g = b + 1; g <= G_; ++g) gst[g] = N_; }
}

// ---------- dense64 (R5-proven): out = act(in @ w^T + b), direct weights ----------
__global__ __launch_bounds__(256) void k_dense64(
    const float* __restrict__ in, const float* __restrict__ w, int wstride,
    const float* __restrict__ b, float* __restrict__ outp, int M, int act)
{
    __shared__ float ti[64 * NPAD];
    __shared__ float to[64 * NPAD];
    int r0 = blockIdx.x * 64;
    for (int i = threadIdx.x; i < 4096; i += 256) {
        int r = i >> 6, c = i & 63; int gr = r0 + r;
        ti[r * NPAD + c] = (gr < M) ? in[(size_t)gr * 64 + c] : 0.f;
    }
    __syncthreads();
    int n = threadIdx.x & 63;
    int jl = __builtin_amdgcn_readfirstlane((threadIdx.x >> 6) << 4);
    float acc[16];
    #pragma unroll
    for (int jj = 0; jj < 16; ++jj) acc[jj] = b[jl + jj];
    for (int kc = 0; kc < 64; kc += 16) {
        float xr[16];
        #pragma unroll
        for (int i = 0; i < 16; ++i) xr[i] = ti[n * NPAD + kc + i];
        #pragma unroll
        for (int jj = 0; jj < 16; ++jj) {
            const float* wr = w + (jl + jj) * wstride + kc;
            #pragma unroll
            for (int i = 0; i < 16; ++i) acc[jj] = fmaf(wr[i], xr[i], acc[jj]);
        }
    }
    #pragma unroll
    for (int jj = 0; jj < 16; ++jj) {
        float v = acc[jj];
        to[n * NPAD + jl + jj] = act ? leaky(v) : v;
    }
    __syncthreads();
    for (int i = threadIdx.x; i < 4096; i += 256) {
        int r = i >> 6, c = i & 63; int gr = r0 + r;
        if (gr < M) outp[(size_t)gr * 64 + c] = to[r * NPAD + c];
    }
}

// ---------- per-node dot(s) with align vectors ----------
__global__ __launch_bounds__(256) void k_node_dot2(
    const float* __restrict__ x, const float* __restrict__ wa,
    const float* __restrict__ wb, float* __restrict__ s,
    float* __restrict__ t, int n, int two)
{
    int gt = blockIdx.x * 256 + threadIdx.x;
    int wid = gt >> 6, lane = threadIdx.x & 63;
    if (wid >= n) return;
    float xv = x[(size_t)wid * 64 + lane];
    float a = xv * wa[lane];
    float bb = two ? xv * wb[lane] : 0.f;
    #pragma unroll
    for (int off = 32; off; off >>= 1) {
        a  += __shfl_down(a, off);
        bb += __shfl_down(bb, off);
    }
    if (lane == 0) { s[wid] = a; if (two) t[wid] = bb; }
}

// ---------- GATE layer: wave per dst node, software-pipelined gather ----------
// edge l+1's u-row + ea vector are loaded before edge l's wredsum chain.
__global__ __launch_bounds__(256) void k_gate_gather(
    const float* __restrict__ u, const float* __restrict__ ea,
    const int* __restrict__ row, const int* __restrict__ csrc, const int* __restrict__ ceid,
    const float* __restrict__ wnl,
    const float* __restrict__ gaw, const float* __restrict__ gab,
    const float* __restrict__ sarr, float* __restrict__ Agg, int N_)
{
    int wid = (blockIdx.x * 256 + threadIdx.x) >> 6;
    int lane = threadIdx.x & 63;
    if (wid >= N_) return;
    float w2[16];
    #pragma unroll
    for (int k = 0; k < 16; ++k) w2[k] = wnl[lane * 80 + 64 + k];
    float g2 = gaw[64 + lane];
    float gb = gab[0];
    float sdst = sarr[wid];
    int beg = row[wid], end = row[wid + 1];
    float m = -INFINITY, d = 0.f, S = 0.f;
    for (int cs = beg; cs < end; cs += 64) {
        int cnt = min(64, end - cs);
        int src_l = 0, eid_l = 0;
        if (lane < cnt) { src_l = csrc[cs + lane]; eid_l = ceid[cs + lane]; }
        // prefetch edge 0
        int s0 = bcasti(src_l, 0), e0 = bcasti(eid_l, 0);
        float ur = u[(size_t)s0 * 64 + lane];
        float4 a0 = *(const float4*)(ea + (size_t)e0 * 16);
        float4 a1 = *(const float4*)(ea + (size_t)e0 * 16 + 4);
        float4 a2 = *(const float4*)(ea + (size_t)e0 * 16 + 8);
        float4 a3 = *(const float4*)(ea + (size_t)e0 * 16 + 12);
        for (int l = 0; l < cnt; ++l) {
            // issue next edge's loads before this edge's reduction chain
            int ln = (l + 1 < cnt) ? l + 1 : l;
            int sn = bcasti(src_l, ln), en = bcasti(eid_l, ln);
            float urn = u[(size_t)sn * 64 + lane];
            float4 b0 = *(const float4*)(ea + (size_t)en * 16);
            float4 b1 = *(const float4*)(ea + (size_t)en * 16 + 4);
            float4 b2 = *(const float4*)(ea + (size_t)en * 16 + 8);
            float4 b3 = *(const float4*)(ea + (size_t)en * 16 + 12);
            float acc = ur;
            acc = fmaf(a0.x, w2[0], acc);  acc = fmaf(a0.y, w2[1], acc);
            acc = fmaf(a0.z, w2[2], acc);  acc = fmaf(a0.w, w2[3], acc);
            acc = fmaf(a1.x, w2[4], acc);  acc = fmaf(a1.y, w2[5], acc);
            acc = fmaf(a1.z, w2[6], acc);  acc = fmaf(a1.w, w2[7], acc);
            acc = fmaf(a2.x, w2[8], acc);  acc = fmaf(a2.y, w2[9], acc);
            acc = fmaf(a2.z, w2[10], acc); acc = fmaf(a2.w, w2[11], acc);
            acc = fmaf(a3.x, w2[12], acc); acc = fmaf(a3.y, w2[13], acc);
            acc = fmaf(a3.z, w2[14], acc); acc = fmaf(a3.w, w2[15], acc);
            float xj = leaky(acc);
            float t = wredsum(xj * g2);
            float sc = leaky(sdst + t + gb);
            float mn = fmaxf(m, sc);
            float c = __expf(m - mn), w = __expf(sc - mn);
            S = S * c + w * xj;
            d = d * c + w;
            m = mn;
            ur = urn; a0 = b0; a1 = b1; a2 = b2; a3 = b3;
        }
    }
    Agg[(size_t)wid * 64 + lane] = S / (d + 1e-16f);
}

// ---------- GAT layer: wave per dst node, pipelined weighted gather ----------
__global__ __launch_bounds__(256) void k_gat_gather(
    const int* __restrict__ row, const int* __restrict__ csrc,
    const float* __restrict__ x, const float* __restrict__ sarr,
    const float* __restrict__ tarr, const float* __restrict__ cb,
    float* __restrict__ Agg, int N_)
{
    int wid = (blockIdx.x * 256 + threadIdx.x) >> 6;
    int lane = threadIdx.x & 63;
    if (wid >= N_) return;
    float sdst = sarr[wid];
    float cbv = cb[0];
    int beg = row[wid], end = row[wid + 1];
    float m = -INFINITY, d = 0.f, S = 0.f;
    for (int cs = beg; cs < end; cs += 64) {
        int cnt = min(64, end - cs);
        float sc_l = -INFINITY; int src_l = 0;
        if (lane < cnt) {
            src_l = csrc[cs + lane];
            sc_l = leaky(sdst + tarr[src_l] + cbv);
        }
        float cmax = wredmax(sc_l);
        float mn = fmaxf(m, cmax);
        float c = __expf(m - mn);
        float w_l = __expf(sc_l - mn);   // 0 for lanes >= cnt
        d = d * c + wredsum(w_l);
        S *= c;
        // rows in groups of 4, one group prefetched ahead; lanes >= cnt have
        // w_l = 0 so rounding cnt up to x4 adds harmless zero-weight rows.
        int cnt4 = (cnt + 3) & ~3;
        int s0 = bcasti(src_l, 0), s1 = bcasti(src_l, 1);
        int s2 = bcasti(src_l, 2), s3 = bcasti(src_l, 3);
        float r0 = x[(size_t)s0 * 64 + lane];
        float r1 = x[(size_t)s1 * 64 + lane];
        float r2 = x[(size_t)s2 * 64 + lane];
        float r3 = x[(size_t)s3 * 64 + lane];
        for (int l = 0; l < cnt4; l += 4) {
            int ln = (l + 4 < cnt4) ? l + 4 : 0;
            int t0 = bcasti(src_l, ln),     t1 = bcasti(src_l, ln + 1);
            int t2 = bcasti(src_l, ln + 2), t3 = bcasti(src_l, ln + 3);
            float p0 = x[(size_t)t0 * 64 + lane];
            float p1 = x[(size_t)t1 * 64 + lane];
            float p2 = x[(size_t)t2 * 64 + lane];
            float p3 = x[(size_t)t3 * 64 + lane];
            float w0 = bcastf(w_l, l),     w1 = bcastf(w_l, l + 1);
            float w2 = bcastf(w_l, l + 2), w3 = bcastf(w_l, l + 3);
            S = fmaf(w0, r0, S); S = fmaf(w1, r1, S);
            S = fmaf(w2, r2, S); S = fmaf(w3, r3, S);
            r0 = p0; r1 = p1; r2 = p2; r3 = p3;
        }
        m = mn;
    }
    Agg[(size_t)wid * 64 + lane] = S / (d + 1e-16f);
}

// ---------- fused node update: 128-row tile, 2 rows/lane ----------
// Each weight fetched per wave now feeds 2 FMAs (rows n and n+64), halving
// scalar-cache pressure vs the 64-row version and doubling work per barrier.
__global__ __launch_bounds__(512, 4) void k_node_update(
    const float* __restrict__ agg, const float* __restrict__ xold,
    const float* __restrict__ wa, const float* __restrict__ ba,
    const float* __restrict__ wih, const float* __restrict__ whh,
    const float* __restrict__ bih, const float* __restrict__ bhh,
    float* __restrict__ xout, int M,
    const float* __restrict__ dwa, const float* __restrict__ dwb,
    float* __restrict__ sout, float* __restrict__ tout)
{
    __shared__ float tA[128 * NPAD];   // agg tile, then h tile, then out tile
    __shared__ float tX[128 * NPAD];   // xold tile; tail reused for dot partials
    int r0 = blockIdx.x * 128;
    // ---- load tiles: float4 global reads, scalar LDS writes (2-way bank = free) ----
    for (int j = threadIdx.x; j < 2048; j += 512) {
        int r = j >> 4, c4 = (j & 15) << 2; int gr = r0 + r;
        float4 av = make_float4(0.f, 0.f, 0.f, 0.f), xv = av;
        if (gr < M) {
            av = *(const float4*)(agg  + (size_t)gr * 64 + c4);
            xv = *(const float4*)(xold + (size_t)gr * 64 + c4);
        }
        int b = r * NPAD + c4;
        tA[b] = av.x; tA[b + 1] = av.y; tA[b + 2] = av.z; tA[b + 3] = av.w;
        tX[b] = xv.x; tX[b + 1] = xv.y; tX[b + 2] = xv.z; tX[b + 3] = xv.w;
    }
    __syncthreads();
    int n = threadIdx.x & 63;
    int jl = __builtin_amdgcn_readfirstlane((threadIdx.x >> 6) << 3);  // 0..56

    // Phase B: h[jl..jl+8) = elu(Agg @ Wa^T + ba), rows n and n+64
    float hvA[8], hvB[8];
    {
        float accA[8], accB[8];
        #pragma unroll
        for (int jj = 0; jj < 8; ++jj) { float bv = ba[jl + jj]; accA[jj] = bv; accB[jj] = bv; }
        for (int kc = 0; kc < 64; kc += 16) {
            float aA[16], aB[16];
            #pragma unroll
            for (int i = 0; i < 16; ++i) {
                aA[i] = tA[n * NPAD + kc + i];
                aB[i] = tA[(n + 64) * NPAD + kc + i];
            }
            #pragma unroll
            for (int jj = 0; jj < 8; ++jj) {
                const float* wr = wa + (jl + jj) * 64 + kc;
                #pragma unroll
                for (int i = 0; i < 16; ++i) {
                    float wv = wr[i];
                    accA[jj] = fmaf(wv, aA[i], accA[jj]);
                    accB[jj] = fmaf(wv, aB[i], accB[jj]);
                }
            }
        }
        #pragma unroll
        for (int jj = 0; jj < 8; ++jj) { hvA[jj] = eluf(accA[jj]); hvB[jj] = eluf(accB[jj]); }
    }
    __syncthreads();          // all phase-B reads of tA done
    #pragma unroll
    for (int jj = 0; jj < 8; ++jj) {
        tA[n * NPAD + jl + jj] = hvA[jj];
        tA[(n + 64) * NPAD + jl + jj] = hvB[jj];
    }
    __syncthreads();          // h tile visible

    // Phase C: GRU. r/z accumulate input+hidden streams; 2 rows share weights.
    float rAc[8], rBc[8], zAc[8], zBc[8], nAc[8], nBc[8], hAc[8], hBc[8];
    #pragma unroll
    for (int jj = 0; jj < 8; ++jj) {
        float brz = bih[jl + jj] + bhh[jl + jj];
        float bz  = bih[64 + jl + jj] + bhh[64 + jl + jj];
        rAc[jj] = brz; rBc[jj] = brz;
        zAc[jj] = bz;  zBc[jj] = bz;
        nAc[jj] = bih[128 + jl + jj]; nBc[jj] = nAc[jj];
        hAc[jj] = bhh[128 + jl + jj]; hBc[jj] = hAc[jj];
    }
    for (int kc = 0; kc < 64; kc += 8) {
        float h0[8], h1[8], x0[8], x1[8];
        #pragma unroll
        for (int i = 0; i < 8; ++i) {
            h0[i] = tA[n * NPAD + kc + i];
            h1[i] = tA[(n + 64) * NPAD + kc + i];
            x0[i] = tX[n * NPAD + kc + i];
            x1[i] = tX[(n + 64) * NPAD + kc + i];
        }
        #pragma unroll
        for (int jj = 0; jj < 8; ++jj) {
            const float* w1 = wih + (jl + jj) * 64 + kc;          // r, input
            const float* w4 = whh + (jl + jj) * 64 + kc;          // r, hidden
            const float* w2 = wih + (64 + jl + jj) * 64 + kc;     // z, input
            const float* w5 = whh + (64 + jl + jj) * 64 + kc;     // z, hidden
            const float* w3 = wih + (128 + jl + jj) * 64 + kc;    // n, input
            const float* w6 = whh + (128 + jl + jj) * 64 + kc;    // n, hidden
            #pragma unroll
            for (int i = 0; i < 8; ++i) {
                float v1 = w1[i], v4 = w4[i], v2 = w2[i];
                float v5 = w5[i], v3 = w3[i], v6 = w6[i];
                rAc[jj] = fmaf(v1, h0[i], rAc[jj]); rAc[jj] = fmaf(v4, x0[i], rAc[jj]);
                rBc[jj] = fmaf(v1, h1[i], rBc[jj]); rBc[jj] = fmaf(v4, x1[i], rBc[jj]);
                zAc[jj] = fmaf(v2, h0[i], zAc[jj]); zAc[jj] = fmaf(v5, x0[i], zAc[jj]);
                zBc[jj] = fmaf(v2, h1[i], zBc[jj]); zBc[jj] = fmaf(v5, x1[i], zBc[jj]);
                nAc[jj] = fmaf(v3, h0[i], nAc[jj]); hAc[jj] = fmaf(v6, x0[i], hAc[jj]);
                nBc[jj] = fmaf(v3, h1[i], nBc[jj]); hBc[jj] = fmaf(v6, x1[i], hBc[jj]);
            }
        }
    }
    #pragma unroll
    for (int jj = 0; jj < 8; ++jj) {
        float r = sigm(rAc[jj]);
        float z = sigm(zAc[jj]);
        float nn = tanhfast(nAc[jj] + r * hAc[jj]);
        float xo = tX[n * NPAD + jl + jj];
        float v = (1.f - z) * nn + z * xo;
        hvA[jj] = fmaxf(v, 0.f);

        float rb = sigm(rBc[jj]);
        float zb = sigm(zBc[jj]);
        float nb_ = tanhfast(nBc[jj] + rb * hBc[jj]);
        float xob = tX[(n + 64) * NPAD + jl + jj];
        float vb = (1.f - zb) * nb_ + zb * xob;
        hvB[jj] = fmaxf(vb, 0.f);
    }
    __syncthreads();          // all phase-C reads of tA/tX done
    #pragma unroll
    for (int jj = 0; jj < 8; ++jj) {
        tA[n * NPAD + jl + jj] = hvA[jj];
        tA[(n + 64) * NPAD + jl + jj] = hvB[jj];
    }
    // Fused align dots: register partials per (row, wave) into tX (dead now),
    // reduced by 128 threads after the barrier. Replaces 16x wredsum epilogue.
    if (sout != nullptr) {
        float paA = 0.f, pbA = 0.f, paB = 0.f, pbB = 0.f;
        #pragma unroll
        for (int jj = 0; jj < 8; ++jj) {
            float wav = dwa[jl + jj], wbv = dwb[jl + jj];
            paA = fmaf(hvA[jj], wav, paA); pbA = fmaf(hvA[jj], wbv, pbA);
            paB = fmaf(hvB[jj], wav, paB); pbB = fmaf(hvB[jj], wbv, pbB);
        }
        int w2i = (threadIdx.x >> 6) << 1;              // slot 0..14
        tX[n * 17 + w2i]            = paA;
        tX[n * 17 + w2i + 1]        = pbA;
        tX[(n + 64) * 17 + w2i]     = paB;
        tX[(n + 64) * 17 + w2i + 1] = pbB;
    }
    __syncthreads();
    for (int j = threadIdx.x; j < 2048; j += 512) {
        int r = j >> 4, c4 = (j & 15) << 2; int gr = r0 + r;
        if (gr < M) {
            int b = r * NPAD + c4;
            float4 ov = make_float4(tA[b], tA[b + 1], tA[b + 2], tA[b + 3]);
            *(float4*)(xout + (size_t)gr * 64 + c4) = ov;
        }
    }
    if (sout != nullptr && threadIdx.x < 128) {
        int r = threadIdx.x; int gr = r0 + r;
        if (gr < M) {
            float sa = 0.f, sb = 0.f;
            #pragma unroll
            for (int w = 0; w < 16; w += 2) { sa += tX[r * 17 + w]; sb += tX[r * 17 + w + 1]; }
            sout[gr] = sa; tout[gr] = sb;
        }
    }
}

// ---------- readout: wave per graph, contiguous segment sum + relu ----------
__global__ __launch_bounds__(256) void k_seg_sum_relu(
    const float* __restrict__ x, const int* __restrict__ gst,
    float* __restrict__ outp, int G_)
{
    int g = (blockIdx.x * 256 + threadIdx.x) >> 6;
    int lane = threadIdx.x & 63;
    if (g >= G_) return;
    float S = 0.f;
    int end = gst[g + 1];
    for (int i = gst[g]; i < end; ++i) S += x[(size_t)i * 64 + lane];
    outp[(size_t)g * 64 + lane] = fmaxf(S, 0.f);
}

// ---------- mol: per-node dot of mix with align part 2 ----------
__global__ __launch_bounds__(256) void k_mol_dots(
    const float* __restrict__ xf, const float* __restrict__ cach,
    const float* __restrict__ maw, float* __restrict__ dd, int n)
{
    int wid = (blockIdx.x * 256 + threadIdx.x) >> 6;
    int lane = threadIdx.x & 63;
    if (wid >= n) return;
    float mix = 0.5f * (xf[(size_t)wid * 64 + lane] + cach[(size_t)wid * 64 + lane]);
    float v = wredsum(mix * maw[64 + lane]);
    if (lane == 0) dd[wid] = v;
}

// ---------- molecule attention: wave per graph, pipelined gather ----------
__global__ __launch_bounds__(256) void k_mol_gather(
    const float* __restrict__ xf, const float* __restrict__ cach,
    const float* __restrict__ stateIn, const int* __restrict__ gst,
    const float* __restrict__ dd,
    const float* __restrict__ maw, const float* __restrict__ mab,
    float* __restrict__ Agg, int G_)
{
    int g = (blockIdx.x * 256 + threadIdx.x) >> 6;
    int lane = threadIdx.x & 63;
    if (g >= G_) return;
    float o = stateIn[(size_t)g * 64 + lane];
    float og = wredsum(o * maw[lane]);
    float mb = mab[0];
    int beg = gst[g], end = gst[g + 1];
    float m = -INFINITY, d = 0.f, S = 0.f;
    for (int cs = beg; cs < end; cs += 64) {
        int cnt = min(64, end - cs);
        float sc_l = -INFINITY;
        if (lane < cnt) sc_l = leaky(og + dd[cs + lane] + mb);
        float cmax = wredmax(sc_l);
        float mn = fmaxf(m, cmax);
        float c = __expf(m - mn);
        float w_l = __expf(sc_l - mn);   // 0 for lanes >= cnt
        d = d * c + wredsum(w_l);
        S *= c;
        int cnt4 = (cnt + 3) & ~3;
        size_t rb = (size_t)cs * 64 + lane;
        float x0 = xf[rb],      c0 = cach[rb];
        float x1 = xf[rb + 64], c1 = cach[rb + 64];
        float x2 = xf[rb + 128], c2 = cach[rb + 128];
        float x3 = xf[rb + 192], c3 = cach[rb + 192];
        for (int l = 0; l < cnt4; l += 4) {
            int ln = (l + 4 < cnt4) ? l + 4 : 0;
            size_t rn = (size_t)(cs + ln) * 64 + lane;
            float y0 = xf[rn],       d0 = cach[rn];
            float y1 = xf[rn + 64],  d1 = cach[rn + 64];
            float y2 = xf[rn + 128], d2 = cach[rn + 128];
            float y3 = xf[rn + 192], d3 = cach[rn + 192];
            float w0 = bcastf(w_l, l),     w1 = bcastf(w_l, l + 1);
            float w2 = bcastf(w_l, l + 2), w3 = bcastf(w_l, l + 3);
            S = fmaf(w0, 0.5f * (x0 + c0), S);
            S = fmaf(w1, 0.5f * (x1 + c1), S);
            S = fmaf(w2, 0.5f * (x2 + c2), S);
            S = fmaf(w3, 0.5f * (x3 + c3), S);
            x0 = y0; c0 = d0; x1 = y1; c1 = d1;
            x2 = y2; c2 = d2; x3 = y3; c3 = d3;
        }
        m = mn;
    }
    Agg[(size_t)g * 64 + lane] = S / (d + 1e-16f);
}

// ---------- final: out[g] = state[g].lin2_w + lin2_b ----------
__global__ __launch_bounds__(256) void k_lin2(
    const float* __restrict__ st, const float* __restrict__ w,
    const float* __restrict__ b, float* __restrict__ outp, int g)
{
    int gt = blockIdx.x * 256 + threadIdx.x;
    int wid = gt >> 6, lane = threadIdx.x & 63;
    if (wid >= g) return;
    float v = st[(size_t)wid * 64 + lane] * w[lane];
    #pragma unroll
    for (int off = 32; off; off >>= 1) v += __shfl_down(v, off);
    if (lane == 0) outp[wid] = v + b[0];
}

// =====================================================================
extern "C" void kernel_launch(void* const* d_in, const int* in_sizes, int n_in,
                              void* d_out, int out_size, void* d_ws, size_t ws_size,
                              hipStream_t stream) {
    const float* raw           = (const float*)d_in[0];
    const int*   ei            = (const int*)d_in[1];
    const float* ea            = (const float*)d_in[2];
    const int*   batch         = (const int*)d_in[3];
    const float* lin1_w        = (const float*)d_in[4];
    const float* lin1_b        = (const float*)d_in[5];
    const float* gate_nl_w     = (const float*)d_in[6];
    const float* gate_nl_b     = (const float*)d_in[7];
    const float* gate_align_w  = (const float*)d_in[8];
    const float* gate_align_b  = (const float*)d_in[9];
    const float* gate_attend_w = (const float*)d_in[10];
    const float* gate_attend_b = (const float*)d_in[11];
    const float* conv_align_w  = (const float*)d_in[12];
    const float* conv_align_b  = (const float*)d_in[13];
    const float* conv_attend_w = (const float*)d_in[14];
    const float* conv_attend_b = (const float*)d_in[15];
    const float* gru_wih       = (const float*)d_in[16];
    const float* gru_whh       = (const float*)d_in[17];
    const float* gru_bih       = (const float*)d_in[18];
    const float* gru_bhh       = (const float*)d_in[19];
    const float* mol_align_w   = (const float*)d_in[20];
    const float* mol_align_b   = (const float*)d_in[21];
    const float* mol_attend_w  = (const float*)d_in[22];
    const float* mol_attend_b  = (const float*)d_in[23];
    const float* mol_wih       = (const float*)d_in[24];
    const float* mol_whh       = (const float*)d_in[25];
    const float* mol_bih       = (const float*)d_in[26];
    const float* mol_bhh       = (const float*)d_in[27];
    const float* lin2_w        = (const float*)d_in[28];
    const float* lin2_b        = (const float*)d_in[29];
    float* out = (float*)d_out;

    const int N = in_sizes[3];
    const int E = in_sizes[1] / 2;
    const int G = out_size;
    const size_t N64 = (size_t)N * 64;
    const size_t G64 = (size_t)G * 64;

    // ---- workspace layout ----
    float* f = (float*)d_ws;
    float* xA    = f;
    float* xB    = xA + N64;
    float* xD    = xB + N64;
    float* Agg   = xD + N64;
    float* u     = Agg + N64;
    float* sN    = u + N64;
    float* tN    = sN + N;
    float* dd    = tN + N;
    float* outS  = dd + N;
    float* outS2 = outS + G64;
    float* aggG  = outS2 + G64;
    int* row  = (int*)(aggG + G64);
    int* csrc = row + (N + 1);
    int* ceid = csrc + E;
    int* bsum = ceid + E;
    int* gst  = bsum + 512;
    int* deg = (int*)Agg;
    int* cur = deg + N;

    const int nb_node64  = (N + 63) / 64;
    const int nb_node128 = (N + 127) / 128;
    const int nb_edge   = (E + 255) / 256;
    const int nb_nodes  = (N + 255) / 256;
    const int nb_waveN  = (N + 3) / 4;
    const int nb_waveG  = (G + 3) / 4;
    const int nb_nodeG  = (G + 127) / 128;

    // ---- CSR build ----
    hipMemsetAsync(deg, 0, (size_t)N * 4, stream);
    k_hist<<<nb_edge, 256, 0, stream>>>(ei, deg, E);
    k_scan1<<<nb_nodes, 256, 0, stream>>>(deg, bsum, N);
    k_scan2<<<1, 512, 0, stream>>>(bsum, nb_nodes);
    k_scan3<<<nb_nodes, 256, 0, stream>>>(deg, bsum, row, cur, N, E);
    k_scatter<<<nb_edge, 256, 0, stream>>>(ei, cur, csrc, ceid, E);
    k_gbounds<<<nb_nodes, 256, 0, stream>>>(batch, gst, N, G);

    // ---- lin1 + gate node-part precompute ----
    k_dense64<<<nb_node64, 256, 0, stream>>>(raw, lin1_w, 64, lin1_b, xA, N, 1);
    k_dense64<<<nb_node64, 256, 0, stream>>>(raw, gate_nl_w, 80, gate_nl_b, u, N, 0);

    // ---- layer 0: GATEConv (xA -> xB); emits align dots for GAT layer 0 ----
    k_node_dot2<<<nb_waveN, 256, 0, stream>>>(xA, gate_align_w, gate_align_w, sN, tN, N, 0);
    k_gate_gather<<<nb_waveN, 256, 0, stream>>>(u, ea, row, csrc, ceid,
                                                gate_nl_w, gate_align_w, gate_align_b,
                                                sN, Agg, N);
    k_node_update<<<nb_node128, 512, 0, stream>>>(Agg, xA, gate_attend_w, gate_attend_b,
                                                  gru_wih, gru_whh, gru_bih, gru_bhh, xB, N,
                                                  conv_align_w, conv_align_w + 64, sN, tN);

    // ---- GAT layer 0 (xB -> xD); emits align dots for GAT layer 1 ----
    k_gat_gather<<<nb_waveN, 256, 0, stream>>>(row, csrc, xB, sN, tN, conv_align_b, Agg, N);
    k_node_update<<<nb_node128, 512, 0, stream>>>(Agg, xB, conv_attend_w, conv_attend_b,
                                                  gru_wih + 12288, gru_whh + 12288,
                                                  gru_bih + 192, gru_bhh + 192, xD, N,
                                                  conv_align_w + 128, conv_align_w + 192, sN, tN);

    // ---- GAT layer 1 (xD -> xA) ----
    k_gat_gather<<<nb_waveN, 256, 0, stream>>>(row, csrc, xD, sN, tN, conv_align_b + 1, Agg, N);
    k_node_update<<<nb_node128, 512, 0, stream>>>(Agg, xD, conv_attend_w + 4096, conv_attend_b + 64,
                                                  gru_wih + 24576, gru_whh + 24576,
                                                  gru_bih + 384, gru_bhh + 384, xA, N,
                                                  nullptr, nullptr, nullptr, nullptr);

    // ---- molecule readout ----
    k_seg_sum_relu<<<nb_waveG, 256, 0, stream>>>(xA, gst, outS, G);

    const float* cachedP[2] = { xD, xA };
    float* sIn = outS; float* sOut = outS2;
    for (int t = 0; t < 2; ++t) {
        k_mol_dots<<<nb_waveN, 256, 0, stream>>>(xA, cachedP[t], mol_align_w, dd, N);
        k_mol_gather<<<nb_waveG, 256, 0, stream>>>(xA, cachedP[t], sIn, gst, dd,
                                                   mol_align_w, mol_align_b, aggG, G);
        k_node_update<<<nb_nodeG, 512, 0, stream>>>(aggG, sIn, mol_attend_w, mol_attend_b,
                                                    mol_wih, mol_whh, mol_bih, mol_bhh, sOut, G,
                                                    nullptr, nullptr, nullptr, nullptr);
        float* tmp = sIn; sIn = sOut; sOut = tmp;
    }

    k_lin2<<<nb_waveG, 256, 0, stream>>>(sIn, lin2_w, lin2_b, out, G);
}

// Round 2
// 1098.926 us; speedup vs baseline: 1.4141x; 1.0117x over previous
//
#include <hip/hip_runtime.h>
#include <math.h>

#define NPAD 65

// ---------- small device helpers ----------
__device__ __forceinline__ float leaky(float x) { return x > 0.f ? x : 0.01f * x; }
__device__ __forceinline__ float eluf(float x)  { return x > 0.f ? x : (__expf(x) - 1.f); }
__device__ __forceinline__ float sigm(float x)  { return 1.f / (1.f + __expf(-x)); }
__device__ __forceinline__ float tanhfast(float x) { return 1.f - 2.f / (__expf(2.f * x) + 1.f); }

__device__ __forceinline__ float bcastf(float v, int k) {
    return __uint_as_float((unsigned)__builtin_amdgcn_readlane((int)__float_as_uint(v), k));
}
__device__ __forceinline__ int bcasti(int v, int k) {
    return __builtin_amdgcn_readlane(v, k);
}
__device__ __forceinline__ float wredsum(float v) {
    #pragma unroll
    for (int off = 32; off; off >>= 1) v += __shfl_xor(v, off);
    return v;
}
__device__ __forceinline__ float wredmax(float v) {
    #pragma unroll
    for (int off = 32; off; off >>= 1) v = fmaxf(v, __shfl_xor(v, off));
    return v;
}

// ================= CSR build =================
__global__ __launch_bounds__(256) void k_hist(const int* __restrict__ ei, int* __restrict__ deg, int E_) {
    int e = blockIdx.x * 256 + threadIdx.x;
    if (e < E_) atomicAdd(&deg[ei[E_ + e]], 1);
}

__global__ __launch_bounds__(256) void k_scan1(const int* __restrict__ deg, int* __restrict__ bsum, int N_) {
    __shared__ int s[256];
    int i = blockIdx.x * 256 + threadIdx.x;
    s[threadIdx.x] = (i < N_) ? deg[i] : 0;
    __syncthreads();
    for (int off = 128; off; off >>= 1) {
        if (threadIdx.x < off) s[threadIdx.x] += s[threadIdx.x + off];
        __syncthreads();
    }
    if (threadIdx.x == 0) bsum[blockIdx.x] = s[0];
}

// parallel exclusive scan of block sums (single block, chunked w/ carry)
__global__ __launch_bounds__(512) void k_scan2(int* __restrict__ bsum, int nb) {
    __shared__ int s[512];
    __shared__ int carry_s;
    if (threadIdx.x == 0) carry_s = 0;
    __syncthreads();
    for (int base = 0; base < nb; base += 512) {
        int t = threadIdx.x;
        int idx = base + t;
        int v = (idx < nb) ? bsum[idx] : 0;
        s[t] = v;
        __syncthreads();
        #pragma unroll
        for (int off = 1; off < 512; off <<= 1) {
            int u = (t >= off) ? s[t - off] : 0;
            __syncthreads();
            s[t] += u;
            __syncthreads();
        }
        int carry = carry_s;
        if (idx < nb) bsum[idx] = carry + s[t] - v;   // exclusive
        __syncthreads();
        if (t == 0) carry_s = carry + s[511];
        __syncthreads();
    }
}

__global__ __launch_bounds__(256) void k_scan3(const int* __restrict__ deg, const int* __restrict__ bsum,
                                               int* __restrict__ row, int* __restrict__ cur, int N_, int E_) {
    __shared__ int s[256];
    int i = blockIdx.x * 256 + threadIdx.x;
    int d = (i < N_) ? deg[i] : 0;
    s[threadIdx.x] = d;
    __syncthreads();
    for (int off = 1; off < 256; off <<= 1) {
        int v = (threadIdx.x >= off) ? s[threadIdx.x - off] : 0;
        __syncthreads();
        s[threadIdx.x] += v;
        __syncthreads();
    }
    if (i < N_) {
        int ex = bsum[blockIdx.x] + s[threadIdx.x] - d;
        row[i] = ex; cur[i] = ex;
    }
    if (i == N_ - 1) row[N_] = E_;
}

__global__ __launch_bounds__(256) void k_scatter(const int* __restrict__ ei, int* __restrict__ cur,
                                                 int* __restrict__ csrc, int* __restrict__ ceid, int E_) {
    int e = blockIdx.x * 256 + threadIdx.x;
    if (e >= E_) return;
    int dst = ei[E_ + e];
    int slot = atomicAdd(&cur[dst], 1);
    csrc[slot] = ei[e];
    ceid[slot] = e;
}

__global__ __launch_bounds__(256) void k_gbounds(const int* __restrict__ batch, int* __restrict__ gst,
                                                 int N_, int G_) {
    int i = blockIdx.x * 256 + threadIdx.x;
    if (i >= N_) return;
    int b = batch[i];
    int prev = (i == 0) ? -1 : batch[i - 1];
    for (int g = prev + 1; g <= b; ++g) gst[g] = i;
    if (i == N_ - 1) { for (int g = b + 1; g <= G_; ++g) gst[g] = N_; }
}

// ---------- dense64 (R5-proven): out = act(in @ w^T + b), direct weights ----------
__global__ __launch_bounds__(256) void k_dense64(
    const float* __restrict__ in, const float* __restrict__ w, int wstride,
    const float* __restrict__ b, float* __restrict__ outp, int M, int act)
{
    __shared__ float ti[64 * NPAD];
    __shared__ float to[64 * NPAD];
    int r0 = blockIdx.x * 64;
    for (int i = threadIdx.x; i < 4096; i += 256) {
        int r = i >> 6, c = i & 63; int gr = r0 + r;
        ti[r * NPAD + c] = (gr < M) ? in[(size_t)gr * 64 + c] : 0.f;
    }
    __syncthreads();
    int n = threadIdx.x & 63;
    int jl = __builtin_amdgcn_readfirstlane((threadIdx.x >> 6) << 4);
    float acc[16];
    #pragma unroll
    for (int jj = 0; jj < 16; ++jj) acc[jj] = b[jl + jj];
    for (int kc = 0; kc < 64; kc += 16) {
        float xr[16];
        #pragma unroll
        for (int i = 0; i < 16; ++i) xr[i] = ti[n * NPAD + kc + i];
        #pragma unroll
        for (int jj = 0; jj < 16; ++jj) {
            const float* wr = w + (jl + jj) * wstride + kc;
            #pragma unroll
            for (int i = 0; i < 16; ++i) acc[jj] = fmaf(wr[i], xr[i], acc[jj]);
        }
    }
    #pragma unroll
    for (int jj = 0; jj < 16; ++jj) {
        float v = acc[jj];
        to[n * NPAD + jl + jj] = act ? leaky(v) : v;
    }
    __syncthreads();
    for (int i = threadIdx.x; i < 4096; i += 256) {
        int r = i >> 6, c = i & 63; int gr = r0 + r;
        if (gr < M) outp[(size_t)gr * 64 + c] = to[r * NPAD + c];
    }
}

// ---------- per-node dot(s) with align vectors ----------
__global__ __launch_bounds__(256) void k_node_dot2(
    const float* __restrict__ x, const float* __restrict__ wa,
    const float* __restrict__ wb, float* __restrict__ s,
    float* __restrict__ t, int n, int two)
{
    int gt = blockIdx.x * 256 + threadIdx.x;
    int wid = gt >> 6, lane = threadIdx.x & 63;
    if (wid >= n) return;
    float xv = x[(size_t)wid * 64 + lane];
    float a = xv * wa[lane];
    float bb = two ? xv * wb[lane] : 0.f;
    #pragma unroll
    for (int off = 32; off; off >>= 1) {
        a  += __shfl_down(a, off);
        bb += __shfl_down(bb, off);
    }
    if (lane == 0) { s[wid] = a; if (two) t[wid] = bb; }
}

// ---------- GATE layer: wave per dst node, 4-edge-batched gather ----------
// 4 independent dot chains + 4-wide interleaved wave reduction + one online
// softmax update per 4 edges: breaks the per-edge serial latency chain.
#define GDOT(acc, A0, A1, A2, A3) \
    acc = fmaf(A0.x, w2[0], acc);  acc = fmaf(A0.y, w2[1], acc);  \
    acc = fmaf(A0.z, w2[2], acc);  acc = fmaf(A0.w, w2[3], acc);  \
    acc = fmaf(A1.x, w2[4], acc);  acc = fmaf(A1.y, w2[5], acc);  \
    acc = fmaf(A1.z, w2[6], acc);  acc = fmaf(A1.w, w2[7], acc);  \
    acc = fmaf(A2.x, w2[8], acc);  acc = fmaf(A2.y, w2[9], acc);  \
    acc = fmaf(A2.z, w2[10], acc); acc = fmaf(A2.w, w2[11], acc); \
    acc = fmaf(A3.x, w2[12], acc); acc = fmaf(A3.y, w2[13], acc); \
    acc = fmaf(A3.z, w2[14], acc); acc = fmaf(A3.w, w2[15], acc);

__global__ __launch_bounds__(256, 4) void k_gate_gather(
    const float* __restrict__ u, const float* __restrict__ ea,
    const int* __restrict__ row, const int* __restrict__ csrc, const int* __restrict__ ceid,
    const float* __restrict__ wnl,
    const float* __restrict__ gaw, const float* __restrict__ gab,
    const float* __restrict__ sarr, float* __restrict__ Agg, int N_)
{
    int wid = (blockIdx.x * 256 + threadIdx.x) >> 6;
    int lane = threadIdx.x & 63;
    if (wid >= N_) return;
    float w2[16];
    #pragma unroll
    for (int k = 0; k < 16; ++k) w2[k] = wnl[lane * 80 + 64 + k];
    float g2 = gaw[64 + lane];
    float gb = gab[0];
    float sdst = sarr[wid];
    int beg = row[wid], end = row[wid + 1];
    float m = -INFINITY, d = 0.f, S = 0.f;
    for (int cs = beg; cs < end; cs += 64) {
        int cnt = min(64, end - cs);
        int src_l = 0, eid_l = 0;
        if (lane < cnt) { src_l = csrc[cs + lane]; eid_l = ceid[cs + lane]; }
        int cnt4 = (cnt + 3) & ~3;
        for (int l = 0; l < cnt4; l += 4) {
            // wave-uniform tail predicates; padded edges use edge l's data, sc=-INF
            int i1 = (l + 1 < cnt) ? l + 1 : l;
            int i2 = (l + 2 < cnt) ? l + 2 : l;
            int i3 = (l + 3 < cnt) ? l + 3 : l;
            int s0 = bcasti(src_l, l),  s1 = bcasti(src_l, i1);
            int s2 = bcasti(src_l, i2), s3 = bcasti(src_l, i3);
            int e0 = bcasti(eid_l, l),  e1 = bcasti(eid_l, i1);
            int e2 = bcasti(eid_l, i2), e3 = bcasti(eid_l, i3);
            float ur0 = u[(size_t)s0 * 64 + lane];
            float ur1 = u[(size_t)s1 * 64 + lane];
            float ur2 = u[(size_t)s2 * 64 + lane];
            float ur3 = u[(size_t)s3 * 64 + lane];
            const float4* pa0 = (const float4*)(ea + (size_t)e0 * 16);
            const float4* pa1 = (const float4*)(ea + (size_t)e1 * 16);
            const float4* pa2 = (const float4*)(ea + (size_t)e2 * 16);
            const float4* pa3 = (const float4*)(ea + (size_t)e3 * 16);
            float4 a00 = pa0[0], a01 = pa0[1], a02 = pa0[2], a03 = pa0[3];
            float4 a10 = pa1[0], a11 = pa1[1], a12 = pa1[2], a13 = pa1[3];
            float4 a20 = pa2[0], a21 = pa2[1], a22 = pa2[2], a23 = pa2[3];
            float4 a30 = pa3[0], a31 = pa3[1], a32 = pa3[2], a33 = pa3[3];
            float acc0 = ur0, acc1 = ur1, acc2 = ur2, acc3 = ur3;
            GDOT(acc0, a00, a01, a02, a03)
            GDOT(acc1, a10, a11, a12, a13)
            GDOT(acc2, a20, a21, a22, a23)
            GDOT(acc3, a30, a31, a32, a33)
            float xj0 = leaky(acc0), xj1 = leaky(acc1);
            float xj2 = leaky(acc2), xj3 = leaky(acc3);
            float t0 = xj0 * g2, t1 = xj1 * g2, t2 = xj2 * g2, t3 = xj3 * g2;
            #pragma unroll
            for (int off = 32; off; off >>= 1) {
                t0 += __shfl_xor(t0, off);
                t1 += __shfl_xor(t1, off);
                t2 += __shfl_xor(t2, off);
                t3 += __shfl_xor(t3, off);
            }
            float sc0 = leaky(sdst + t0 + gb);
            float sc1 = (l + 1 < cnt) ? leaky(sdst + t1 + gb) : -INFINITY;
            float sc2 = (l + 2 < cnt) ? leaky(sdst + t2 + gb) : -INFINITY;
            float sc3 = (l + 3 < cnt) ? leaky(sdst + t3 + gb) : -INFINITY;
            float mn = fmaxf(fmaxf(m, sc0), fmaxf(fmaxf(sc1, sc2), sc3));
            float c = __expf(m - mn);
            float q0 = __expf(sc0 - mn), q1 = __expf(sc1 - mn);
            float q2 = __expf(sc2 - mn), q3 = __expf(sc3 - mn);
            S = S * c;
            S = fmaf(q0, xj0, S); S = fmaf(q1, xj1, S);
            S = fmaf(q2, xj2, S); S = fmaf(q3, xj3, S);
            d = d * c + ((q0 + q1) + (q2 + q3));
            m = mn;
        }
    }
    Agg[(size_t)wid * 64 + lane] = S / (d + 1e-16f);
}

// ---------- GAT layer: wave per dst node, pipelined weighted gather ----------
__global__ __launch_bounds__(256) void k_gat_gather(
    const int* __restrict__ row, const int* __restrict__ csrc,
    const float* __restrict__ x, const float* __restrict__ sarr,
    const float* __restrict__ tarr, const float* __restrict__ cb,
    float* __restrict__ Agg, int N_)
{
    int wid = (blockIdx.x * 256 + threadIdx.x) >> 6;
    int lane = threadIdx.x & 63;
    if (wid >= N_) return;
    float sdst = sarr[wid];
    float cbv = cb[0];
    int beg = row[wid], end = row[wid + 1];
    float m = -INFINITY, d = 0.f, S = 0.f;
    for (int cs = beg; cs < end; cs += 64) {
        int cnt = min(64, end - cs);
        float sc_l = -INFINITY; int src_l = 0;
        if (lane < cnt) {
            src_l = csrc[cs + lane];
            sc_l = leaky(sdst + tarr[src_l] + cbv);
        }
        float cmax = wredmax(sc_l);
        float mn = fmaxf(m, cmax);
        float c = __expf(m - mn);
        float w_l = __expf(sc_l - mn);   // 0 for lanes >= cnt
        d = d * c + wredsum(w_l);
        S *= c;
        // rows in groups of 4, one group prefetched ahead; lanes >= cnt have
        // w_l = 0 so rounding cnt up to x4 adds harmless zero-weight rows.
        int cnt4 = (cnt + 3) & ~3;
        int s0 = bcasti(src_l, 0), s1 = bcasti(src_l, 1);
        int s2 = bcasti(src_l, 2), s3 = bcasti(src_l, 3);
        float r0 = x[(size_t)s0 * 64 + lane];
        float r1 = x[(size_t)s1 * 64 + lane];
        float r2 = x[(size_t)s2 * 64 + lane];
        float r3 = x[(size_t)s3 * 64 + lane];
        for (int l = 0; l < cnt4; l += 4) {
            int ln = (l + 4 < cnt4) ? l + 4 : 0;
            int t0 = bcasti(src_l, ln),     t1 = bcasti(src_l, ln + 1);
            int t2 = bcasti(src_l, ln + 2), t3 = bcasti(src_l, ln + 3);
            float p0 = x[(size_t)t0 * 64 + lane];
            float p1 = x[(size_t)t1 * 64 + lane];
            float p2 = x[(size_t)t2 * 64 + lane];
            float p3 = x[(size_t)t3 * 64 + lane];
            float w0 = bcastf(w_l, l),     w1 = bcastf(w_l, l + 1);
            float w2 = bcastf(w_l, l + 2), w3 = bcastf(w_l, l + 3);
            S = fmaf(w0, r0, S); S = fmaf(w1, r1, S);
            S = fmaf(w2, r2, S); S = fmaf(w3, r3, S);
            r0 = p0; r1 = p1; r2 = p2; r3 = p3;
        }
        m = mn;
    }
    Agg[(size_t)wid * 64 + lane] = S / (d + 1e-16f);
}

// ---------- fused node update: 128-row tile, 2 rows/lane ----------
// Each weight fetched per wave now feeds 2 FMAs (rows n and n+64), halving
// scalar-cache pressure vs the 64-row version and doubling work per barrier.
__global__ __launch_bounds__(512, 4) void k_node_update(
    const float* __restrict__ agg, const float* __restrict__ xold,
    const float* __restrict__ wa, const float* __restrict__ ba,
    const float* __restrict__ wih, const float* __restrict__ whh,
    const float* __restrict__ bih, const float* __restrict__ bhh,
    float* __restrict__ xout, int M,
    const float* __restrict__ dwa, const float* __restrict__ dwb,
    float* __restrict__ sout, float* __restrict__ tout)
{
    __shared__ float tA[128 * NPAD];   // agg tile, then h tile, then out tile
    __shared__ float tX[128 * NPAD];   // xold tile; tail reused for dot partials
    int r0 = blockIdx.x * 128;
    // ---- load tiles: float4 global reads, scalar LDS writes (2-way bank = free) ----
    for (int j = threadIdx.x; j < 2048; j += 512) {
        int r = j >> 4, c4 = (j & 15) << 2; int gr = r0 + r;
        float4 av = make_float4(0.f, 0.f, 0.f, 0.f), xv = av;
        if (gr < M) {
            av = *(const float4*)(agg  + (size_t)gr * 64 + c4);
            xv = *(const float4*)(xold + (size_t)gr * 64 + c4);
        }
        int b = r * NPAD + c4;
        tA[b] = av.x; tA[b + 1] = av.y; tA[b + 2] = av.z; tA[b + 3] = av.w;
        tX[b] = xv.x; tX[b + 1] = xv.y; tX[b + 2] = xv.z; tX[b + 3] = xv.w;
    }
    __syncthreads();
    int n = threadIdx.x & 63;
    int jl = __builtin_amdgcn_readfirstlane((threadIdx.x >> 6) << 3);  // 0..56

    // Phase B: h[jl..jl+8) = elu(Agg @ Wa^T + ba), rows n and n+64
    float hvA[8], hvB[8];
    {
        float accA[8], accB[8];
        #pragma unroll
        for (int jj = 0; jj < 8; ++jj) { float bv = ba[jl + jj]; accA[jj] = bv; accB[jj] = bv; }
        for (int kc = 0; kc < 64; kc += 16) {
            float aA[16], aB[16];
            #pragma unroll
            for (int i = 0; i < 16; ++i) {
                aA[i] = tA[n * NPAD + kc + i];
                aB[i] = tA[(n + 64) * NPAD + kc + i];
            }
            #pragma unroll
            for (int jj = 0; jj < 8; ++jj) {
                const float* wr = wa + (jl + jj) * 64 + kc;
                #pragma unroll
                for (int i = 0; i < 16; ++i) {
                    float wv = wr[i];
                    accA[jj] = fmaf(wv, aA[i], accA[jj]);
                    accB[jj] = fmaf(wv, aB[i], accB[jj]);
                }
            }
        }
        #pragma unroll
        for (int jj = 0; jj < 8; ++jj) { hvA[jj] = eluf(accA[jj]); hvB[jj] = eluf(accB[jj]); }
    }
    __syncthreads();          // all phase-B reads of tA done
    #pragma unroll
    for (int jj = 0; jj < 8; ++jj) {
        tA[n * NPAD + jl + jj] = hvA[jj];
        tA[(n + 64) * NPAD + jl + jj] = hvB[jj];
    }
    __syncthreads();          // h tile visible

    // Phase C: GRU. r/z accumulate input+hidden streams; 2 rows share weights.
    float rAc[8], rBc[8], zAc[8], zBc[8], nAc[8], nBc[8], hAc[8], hBc[8];
    #pragma unroll
    for (int jj = 0; jj < 8; ++jj) {
        float brz = bih[jl + jj] + bhh[jl + jj];
        float bz  = bih[64 + jl + jj] + bhh[64 + jl + jj];
        rAc[jj] = brz; rBc[jj] = brz;
        zAc[jj] = bz;  zBc[jj] = bz;
        nAc[jj] = bih[128 + jl + jj]; nBc[jj] = nAc[jj];
        hAc[jj] = bhh[128 + jl + jj]; hBc[jj] = hAc[jj];
    }
    for (int kc = 0; kc < 64; kc += 8) {
        float h0[8], h1[8], x0[8], x1[8];
        #pragma unroll
        for (int i = 0; i < 8; ++i) {
            h0[i] = tA[n * NPAD + kc + i];
            h1[i] = tA[(n + 64) * NPAD + kc + i];
            x0[i] = tX[n * NPAD + kc + i];
            x1[i] = tX[(n + 64) * NPAD + kc + i];
        }
        #pragma unroll
        for (int jj = 0; jj < 8; ++jj) {
            const float* w1 = wih + (jl + jj) * 64 + kc;          // r, input
            const float* w4 = whh + (jl + jj) * 64 + kc;          // r, hidden
            const float* w2 = wih + (64 + jl + jj) * 64 + kc;     // z, input
            const float* w5 = whh + (64 + jl + jj) * 64 + kc;     // z, hidden
            const float* w3 = wih + (128 + jl + jj) * 64 + kc;    // n, input
            const float* w6 = whh + (128 + jl + jj) * 64 + kc;    // n, hidden
            #pragma unroll
            for (int i = 0; i < 8; ++i) {
                float v1 = w1[i], v4 = w4[i], v2 = w2[i];
                float v5 = w5[i], v3 = w3[i], v6 = w6[i];
                rAc[jj] = fmaf(v1, h0[i], rAc[jj]); rAc[jj] = fmaf(v4, x0[i], rAc[jj]);
                rBc[jj] = fmaf(v1, h1[i], rBc[jj]); rBc[jj] = fmaf(v4, x1[i], rBc[jj]);
                zAc[jj] = fmaf(v2, h0[i], zAc[jj]); zAc[jj] = fmaf(v5, x0[i], zAc[jj]);
                zBc[jj] = fmaf(v2, h1[i], zBc[jj]); zBc[jj] = fmaf(v5, x1[i], zBc[jj]);
                nAc[jj] = fmaf(v3, h0[i], nAc[jj]); hAc[jj] = fmaf(v6, x0[i], hAc[jj]);
                nBc[jj] = fmaf(v3, h1[i], nBc[jj]); hBc[jj] = fmaf(v6, x1[i], hBc[jj]);
            }
        }
    }
    #pragma unroll
    for (int jj = 0; jj < 8; ++jj) {
        float r = sigm(rAc[jj]);
        float z = sigm(zAc[jj]);
        float nn = tanhfast(nAc[jj] + r * hAc[jj]);
        float xo = tX[n * NPAD + jl + jj];
        float v = (1.f - z) * nn + z * xo;
        hvA[jj] = fmaxf(v, 0.f);

        float rb = sigm(rBc[jj]);
        float zb = sigm(zBc[jj]);
        float nb_ = tanhfast(nBc[jj] + rb * hBc[jj]);
        float xob = tX[(n + 64) * NPAD + jl + jj];
        float vb = (1.f - zb) * nb_ + zb * xob;
        hvB[jj] = fmaxf(vb, 0.f);
    }
    __syncthreads();          // all phase-C reads of tA/tX done
    #pragma unroll
    for (int jj = 0; jj < 8; ++jj) {
        tA[n * NPAD + jl + jj] = hvA[jj];
        tA[(n + 64) * NPAD + jl + jj] = hvB[jj];
    }
    // Fused align dots: register partials per (row, wave) into tX (dead now),
    // reduced by 128 threads after the barrier. Replaces 16x wredsum epilogue.
    if (sout != nullptr) {
        float paA = 0.f, pbA = 0.f, paB = 0.f, pbB = 0.f;
        #pragma unroll
        for (int jj = 0; jj < 8; ++jj) {
            float wav = dwa[jl + jj], wbv = dwb[jl + jj];
            paA = fmaf(hvA[jj], wav, paA); pbA = fmaf(hvA[jj], wbv, pbA);
            paB = fmaf(hvB[jj], wav, paB); pbB = fmaf(hvB[jj], wbv, pbB);
        }
        int w2i = (threadIdx.x >> 6) << 1;              // slot 0..14
        tX[n * 17 + w2i]            = paA;
        tX[n * 17 + w2i + 1]        = pbA;
        tX[(n + 64) * 17 + w2i]     = paB;
        tX[(n + 64) * 17 + w2i + 1] = pbB;
    }
    __syncthreads();
    for (int j = threadIdx.x; j < 2048; j += 512) {
        int r = j >> 4, c4 = (j & 15) << 2; int gr = r0 + r;
        if (gr < M) {
            int b = r * NPAD + c4;
            float4 ov = make_float4(tA[b], tA[b + 1], tA[b + 2], tA[b + 3]);
            *(float4*)(xout + (size_t)gr * 64 + c4) = ov;
        }
    }
    if (sout != nullptr && threadIdx.x < 128) {
        int r = threadIdx.x; int gr = r0 + r;
        if (gr < M) {
            float sa = 0.f, sb = 0.f;
            #pragma unroll
            for (int w = 0; w < 16; w += 2) { sa += tX[r * 17 + w]; sb += tX[r * 17 + w + 1]; }
            sout[gr] = sa; tout[gr] = sb;
        }
    }
}

// ---------- readout: wave per graph, contiguous segment sum + relu ----------
__global__ __launch_bounds__(256) void k_seg_sum_relu(
    const float* __restrict__ x, const int* __restrict__ gst,
    float* __restrict__ outp, int G_)
{
    int g = (blockIdx.x * 256 + threadIdx.x) >> 6;
    int lane = threadIdx.x & 63;
    if (g >= G_) return;
    float S = 0.f;
    int end = gst[g + 1];
    for (int i = gst[g]; i < end; ++i) S += x[(size_t)i * 64 + lane];
    outp[(size_t)g * 64 + lane] = fmaxf(S, 0.f);
}

// ---------- mol: per-node dot of mix with align part 2 ----------
__global__ __launch_bounds__(256) void k_mol_dots(
    const float* __restrict__ xf, const float* __restrict__ cach,
    const float* __restrict__ maw, float* __restrict__ dd, int n)
{
    int wid = (blockIdx.x * 256 + threadIdx.x) >> 6;
    int lane = threadIdx.x & 63;
    if (wid >= n) return;
    float mix = 0.5f * (xf[(size_t)wid * 64 + lane] + cach[(size_t)wid * 64 + lane]);
    float v = wredsum(mix * maw[64 + lane]);
    if (lane == 0) dd[wid] = v;
}

// ---------- molecule attention: wave per graph, pipelined gather ----------
__global__ __launch_bounds__(256) void k_mol_gather(
    const float* __restrict__ xf, const float* __restrict__ cach,
    const float* __restrict__ stateIn, const int* __restrict__ gst,
    const float* __restrict__ dd,
    const float* __restrict__ maw, const float* __restrict__ mab,
    float* __restrict__ Agg, int G_)
{
    int g = (blockIdx.x * 256 + threadIdx.x) >> 6;
    int lane = threadIdx.x & 63;
    if (g >= G_) return;
    float o = stateIn[(size_t)g * 64 + lane];
    float og = wredsum(o * maw[lane]);
    float mb = mab[0];
    int beg = gst[g], end = gst[g + 1];
    float m = -INFINITY, d = 0.f, S = 0.f;
    for (int cs = beg; cs < end; cs += 64) {
        int cnt = min(64, end - cs);
        float sc_l = -INFINITY;
        if (lane < cnt) sc_l = leaky(og + dd[cs + lane] + mb);
        float cmax = wredmax(sc_l);
        float mn = fmaxf(m, cmax);
        float c = __expf(m - mn);
        float w_l = __expf(sc_l - mn);   // 0 for lanes >= cnt
        d = d * c + wredsum(w_l);
        S *= c;
        int cnt4 = (cnt + 3) & ~3;
        size_t rb = (size_t)cs * 64 + lane;
        float x0 = xf[rb],      c0 = cach[rb];
        float x1 = xf[rb + 64], c1 = cach[rb + 64];
        float x2 = xf[rb + 128], c2 = cach[rb + 128];
        float x3 = xf[rb + 192], c3 = cach[rb + 192];
        for (int l = 0; l < cnt4; l += 4) {
            int ln = (l + 4 < cnt4) ? l + 4 : 0;
            size_t rn = (size_t)(cs + ln) * 64 + lane;
            float y0 = xf[rn],       d0 = cach[rn];
            float y1 = xf[rn + 64],  d1 = cach[rn + 64];
            float y2 = xf[rn + 128], d2 = cach[rn + 128];
            float y3 = xf[rn + 192], d3 = cach[rn + 192];
            float w0 = bcastf(w_l, l),     w1 = bcastf(w_l, l + 1);
            float w2 = bcastf(w_l, l + 2), w3 = bcastf(w_l, l + 3);
            S = fmaf(w0, 0.5f * (x0 + c0), S);
            S = fmaf(w1, 0.5f * (x1 + c1), S);
            S = fmaf(w2, 0.5f * (x2 + c2), S);
            S = fmaf(w3, 0.5f * (x3 + c3), S);
            x0 = y0; c0 = d0; x1 = y1; c1 = d1;
            x2 = y2; c2 = d2; x3 = y3; c3 = d3;
        }
        m = mn;
    }
    Agg[(size_t)g * 64 + lane] = S / (d + 1e-16f);
}

// ---------- final: out[g] = state[g].lin2_w + lin2_b ----------
__global__ __launch_bounds__(256) void k_lin2(
    const float* __restrict__ st, const float* __restrict__ w,
    const float* __restrict__ b, float* __restrict__ outp, int g)
{
    int gt = blockIdx.x * 256 + threadIdx.x;
    int wid = gt >> 6, lane = threadIdx.x & 63;
    if (wid >= g) return;
    float v = st[(size_t)wid * 64 + lane] * w[lane];
    #pragma unroll
    for (int off = 32; off; off >>= 1) v += __shfl_down(v, off);
    if (lane == 0) outp[wid] = v + b[0];
}

// =====================================================================
extern "C" void kernel_launch(void* const* d_in, const int* in_sizes, int n_in,
                              void* d_out, int out_size, void* d_ws, size_t ws_size,
                              hipStream_t stream) {
    const float* raw           = (const float*)d_in[0];
    const int*   ei            = (const int*)d_in[1];
    const float* ea            = (const float*)d_in[2];
    const int*   batch         = (const int*)d_in[3];
    const float* lin1_w        = (const float*)d_in[4];
    const float* lin1_b        = (const float*)d_in[5];
    const float* gate_nl_w     = (const float*)d_in[6];
    const float* gate_nl_b     = (const float*)d_in[7];
    const float* gate_align_w  = (const float*)d_in[8];
    const float* gate_align_b  = (const float*)d_in[9];
    const float* gate_attend_w = (const float*)d_in[10];
    const float* gate_attend_b = (const float*)d_in[11];
    const float* conv_align_w  = (const float*)d_in[12];
    const float* conv_align_b  = (const float*)d_in[13];
    const float* conv_attend_w = (const float*)d_in[14];
    const float* conv_attend_b = (const float*)d_in[15];
    const float* gru_wih       = (const float*)d_in[16];
    const float* gru_whh       = (const float*)d_in[17];
    const float* gru_bih       = (const float*)d_in[18];
    const float* gru_bhh       = (const float*)d_in[19];
    const float* mol_align_w   = (const float*)d_in[20];
    const float* mol_align_b   = (const float*)d_in[21];
    const float* mol_attend_w  = (const float*)d_in[22];
    const float* mol_attend_b  = (const float*)d_in[23];
    const float* mol_wih       = (const float*)d_in[24];
    const float* mol_whh       = (const float*)d_in[25];
    const float* mol_bih       = (const float*)d_in[26];
    const float* mol_bhh       = (const float*)d_in[27];
    const float* lin2_w        = (const float*)d_in[28];
    const float* lin2_b        = (const float*)d_in[29];
    float* out = (float*)d_out;

    const int N = in_sizes[3];
    const int E = in_sizes[1] / 2;
    const int G = out_size;
    const size_t N64 = (size_t)N * 64;
    const size_t G64 = (size_t)G * 64;

    // ---- workspace layout ----
    float* f = (float*)d_ws;
    float* xA    = f;
    float* xB    = xA + N64;
    float* xD    = xB + N64;
    float* Agg   = xD + N64;
    float* u     = Agg + N64;
    float* sN    = u + N64;
    float* tN    = sN + N;
    float* dd    = tN + N;
    float* outS  = dd + N;
    float* outS2 = outS + G64;
    float* aggG  = outS2 + G64;
    int* row  = (int*)(aggG + G64);
    int* csrc = row + (N + 1);
    int* ceid = csrc + E;
    int* bsum = ceid + E;
    int* gst  = bsum + 512;
    int* deg = (int*)Agg;
    int* cur = deg + N;

    const int nb_node64  = (N + 63) / 64;
    const int nb_node128 = (N + 127) / 128;
    const int nb_edge   = (E + 255) / 256;
    const int nb_nodes  = (N + 255) / 256;
    const int nb_waveN  = (N + 3) / 4;
    const int nb_waveG  = (G + 3) / 4;
    const int nb_nodeG  = (G + 127) / 128;

    // ---- CSR build ----
    hipMemsetAsync(deg, 0, (size_t)N * 4, stream);
    k_hist<<<nb_edge, 256, 0, stream>>>(ei, deg, E);
    k_scan1<<<nb_nodes, 256, 0, stream>>>(deg, bsum, N);
    k_scan2<<<1, 512, 0, stream>>>(bsum, nb_nodes);
    k_scan3<<<nb_nodes, 256, 0, stream>>>(deg, bsum, row, cur, N, E);
    k_scatter<<<nb_edge, 256, 0, stream>>>(ei, cur, csrc, ceid, E);
    k_gbounds<<<nb_nodes, 256, 0, stream>>>(batch, gst, N, G);

    // ---- lin1 + gate node-part precompute ----
    k_dense64<<<nb_node64, 256, 0, stream>>>(raw, lin1_w, 64, lin1_b, xA, N, 1);
    k_dense64<<<nb_node64, 256, 0, stream>>>(raw, gate_nl_w, 80, gate_nl_b, u, N, 0);

    // ---- layer 0: GATEConv (xA -> xB); emits align dots for GAT layer 0 ----
    k_node_dot2<<<nb_waveN, 256, 0, stream>>>(xA, gate_align_w, gate_align_w, sN, tN, N, 0);
    k_gate_gather<<<nb_waveN, 256, 0, stream>>>(u, ea, row, csrc, ceid,
                                                gate_nl_w, gate_align_w, gate_align_b,
                                                sN, Agg, N);
    k_node_update<<<nb_node128, 512, 0, stream>>>(Agg, xA, gate_attend_w, gate_attend_b,
                                                  gru_wih, gru_whh, gru_bih, gru_bhh, xB, N,
                                                  conv_align_w, conv_align_w + 64, sN, tN);

    // ---- GAT layer 0 (xB -> xD); emits align dots for GAT layer 1 ----
    k_gat_gather<<<nb_waveN, 256, 0, stream>>>(row, csrc, xB, sN, tN, conv_align_b, Agg, N);
    k_node_update<<<nb_node128, 512, 0, stream>>>(Agg, xB, conv_attend_w, conv_attend_b,
                                                  gru_wih + 12288, gru_whh + 12288,
                                                  gru_bih + 192, gru_bhh + 192, xD, N,
                                                  conv_align_w + 128, conv_align_w + 192, sN, tN);

    // ---- GAT layer 1 (xD -> xA) ----
    k_gat_gather<<<nb_waveN, 256, 0, stream>>>(row, csrc, xD, sN, tN, conv_align_b + 1, Agg, N);
    k_node_update<<<nb_node128, 512, 0, stream>>>(Agg, xD, conv_attend_w + 4096, conv_attend_b + 64,
                                                  gru_wih + 24576, gru_whh + 24576,
                                                  gru_bih + 384, gru_bhh + 384, xA, N,
                                                  nullptr, nullptr, nullptr, nullptr);

    // ---- molecule readout ----
    k_seg_sum_relu<<<nb_waveG, 256, 0, stream>>>(xA, gst, outS, G);

    const float* cachedP[2] = { xD, xA };
    float* sIn = outS; float* sOut = outS2;
    for (int t = 0; t < 2; ++t) {
        k_mol_dots<<<nb_waveN, 256, 0, stream>>>(xA, cachedP[t], mol_align_w, dd, N);
        k_mol_gather<<<nb_waveG, 256, 0, stream>>>(xA, cachedP[t], sIn, gst, dd,
                                                   mol_align_w, mol_align_b, aggG, G);
        k_node_update<<<nb_nodeG, 512, 0, stream>>>(aggG, sIn, mol_attend_w, mol_attend_b,
                                                    mol_wih, mol_whh, mol_bih, mol_bhh, sOut, G,
                                                    nullptr, nullptr, nullptr, nullptr);
        float* tmp = sIn; sIn = sOut; sOut = tmp;
    }

    k_lin2<<<nb_waveG, 256, 0, stream>>>(sIn, lin2_w, lin2_b, out, G);
}

// Round 3
// 1091.300 us; speedup vs baseline: 1.4240x; 1.0070x over previous
//
#include <hip/hip_runtime.h>
#include <math.h>

#define NPAD 65

// ---------- small device helpers ----------
__device__ __forceinline__ float leaky(float x) { return x > 0.f ? x : 0.01f * x; }
__device__ __forceinline__ float eluf(float x)  { return x > 0.f ? x : (__expf(x) - 1.f); }
__device__ __forceinline__ float sigm(float x)  { return 1.f / (1.f + __expf(-x)); }
__device__ __forceinline__ float tanhfast(float x) { return 1.f - 2.f / (__expf(2.f * x) + 1.f); }

__device__ __forceinline__ float bcastf(float v, int k) {
    return __uint_as_float((unsigned)__builtin_amdgcn_readlane((int)__float_as_uint(v), k));
}
__device__ __forceinline__ int bcasti(int v, int k) {
    return __builtin_amdgcn_readlane(v, k);
}
__device__ __forceinline__ float wredsum(float v) {
    #pragma unroll
    for (int off = 32; off; off >>= 1) v += __shfl_xor(v, off);
    return v;
}
__device__ __forceinline__ float wredmax(float v) {
    #pragma unroll
    for (int off = 32; off; off >>= 1) v = fmaxf(v, __shfl_xor(v, off));
    return v;
}

// ================= CSR build =================
__global__ __launch_bounds__(256) void k_hist(const int* __restrict__ ei, int* __restrict__ deg, int E_) {
    int e = blockIdx.x * 256 + threadIdx.x;
    if (e < E_) atomicAdd(&deg[ei[E_ + e]], 1);
}

__global__ __launch_bounds__(256) void k_scan1(const int* __restrict__ deg, int* __restrict__ bsum, int N_) {
    __shared__ int s[256];
    int i = blockIdx.x * 256 + threadIdx.x;
    s[threadIdx.x] = (i < N_) ? deg[i] : 0;
    __syncthreads();
    for (int off = 128; off; off >>= 1) {
        if (threadIdx.x < off) s[threadIdx.x] += s[threadIdx.x + off];
        __syncthreads();
    }
    if (threadIdx.x == 0) bsum[blockIdx.x] = s[0];
}

// parallel exclusive scan of block sums (single block, chunked w/ carry)
__global__ __launch_bounds__(512) void k_scan2(int* __restrict__ bsum, int nb) {
    __shared__ int s[512];
    __shared__ int carry_s;
    if (threadIdx.x == 0) carry_s = 0;
    __syncthreads();
    for (int base = 0; base < nb; base += 512) {
        int t = threadIdx.x;
        int idx = base + t;
        int v = (idx < nb) ? bsum[idx] : 0;
        s[t] = v;
        __syncthreads();
        #pragma unroll
        for (int off = 1; off < 512; off <<= 1) {
            int u = (t >= off) ? s[t - off] : 0;
            __syncthreads();
            s[t] += u;
            __syncthreads();
        }
        int carry = carry_s;
        if (idx < nb) bsum[idx] = carry + s[t] - v;   // exclusive
        __syncthreads();
        if (t == 0) carry_s = carry + s[511];
        __syncthreads();
    }
}

__global__ __launch_bounds__(256) void k_scan3(const int* __restrict__ deg, const int* __restrict__ bsum,
                                               int* __restrict__ row, int* __restrict__ cur, int N_, int E_) {
    __shared__ int s[256];
    int i = blockIdx.x * 256 + threadIdx.x;
    int d = (i < N_) ? deg[i] : 0;
    s[threadIdx.x] = d;
    __syncthreads();
    for (int off = 1; off < 256; off <<= 1) {
        int v = (threadIdx.x >= off) ? s[threadIdx.x - off] : 0;
        __syncthreads();
        s[threadIdx.x] += v;
        __syncthreads();
    }
    if (i < N_) {
        int ex = bsum[blockIdx.x] + s[threadIdx.x] - d;
        row[i] = ex; cur[i] = ex;
    }
    if (i == N_ - 1) row[N_] = E_;
}

__global__ __launch_bounds__(256) void k_scatter(const int* __restrict__ ei, int* __restrict__ cur,
                                                 int* __restrict__ csrc, int* __restrict__ ceid, int E_) {
    int e = blockIdx.x * 256 + threadIdx.x;
    if (e >= E_) return;
    int dst = ei[E_ + e];
    int slot = atomicAdd(&cur[dst], 1);
    csrc[slot] = ei[e];
    ceid[slot] = e;
}

__global__ __launch_bounds__(256) void k_gbounds(const int* __restrict__ batch, int* __restrict__ gst,
                                                 int N_, int G_) {
    int i = blockIdx.x * 256 + threadIdx.x;
    if (i >= N_) return;
    int b = batch[i];
    int prev = (i == 0) ? -1 : batch[i - 1];
    for (int g = prev + 1; g <= b; ++g) gst[g] = i;
    if (i == N_ - 1) { for (int g = b + 1; g <= G_; ++g) gst[g] = N_; }
}

// ---------- dense64 (R5-proven): out = act(in @ w^T + b), direct weights ----------
__global__ __launch_bounds__(256) void k_dense64(
    const float* __restrict__ in, const float* __restrict__ w, int wstride,
    const float* __restrict__ b, float* __restrict__ outp, int M, int act)
{
    __shared__ float ti[64 * NPAD];
    __shared__ float to[64 * NPAD];
    int r0 = blockIdx.x * 64;
    for (int i = threadIdx.x; i < 4096; i += 256) {
        int r = i >> 6, c = i & 63; int gr = r0 + r;
        ti[r * NPAD + c] = (gr < M) ? in[(size_t)gr * 64 + c] : 0.f;
    }
    __syncthreads();
    int n = threadIdx.x & 63;
    int jl = __builtin_amdgcn_readfirstlane((threadIdx.x >> 6) << 4);
    float acc[16];
    #pragma unroll
    for (int jj = 0; jj < 16; ++jj) acc[jj] = b[jl + jj];
    for (int kc = 0; kc < 64; kc += 16) {
        float xr[16];
        #pragma unroll
        for (int i = 0; i < 16; ++i) xr[i] = ti[n * NPAD + kc + i];
        #pragma unroll
        for (int jj = 0; jj < 16; ++jj) {
            const float* wr = w + (jl + jj) * wstride + kc;
            #pragma unroll
            for (int i = 0; i < 16; ++i) acc[jj] = fmaf(wr[i], xr[i], acc[jj]);
        }
    }
    #pragma unroll
    for (int jj = 0; jj < 16; ++jj) {
        float v = acc[jj];
        to[n * NPAD + jl + jj] = act ? leaky(v) : v;
    }
    __syncthreads();
    for (int i = threadIdx.x; i < 4096; i += 256) {
        int r = i >> 6, c = i & 63; int gr = r0 + r;
        if (gr < M) outp[(size_t)gr * 64 + c] = to[r * NPAD + c];
    }
}

// ---------- per-node dot(s) with align vectors ----------
__global__ __launch_bounds__(256) void k_node_dot2(
    const float* __restrict__ x, const float* __restrict__ wa,
    const float* __restrict__ wb, float* __restrict__ s,
    float* __restrict__ t, int n, int two)
{
    int gt = blockIdx.x * 256 + threadIdx.x;
    int wid = gt >> 6, lane = threadIdx.x & 63;
    if (wid >= n) return;
    float xv = x[(size_t)wid * 64 + lane];
    float a = xv * wa[lane];
    float bb = two ? xv * wb[lane] : 0.f;
    #pragma unroll
    for (int off = 32; off; off >>= 1) {
        a  += __shfl_down(a, off);
        bb += __shfl_down(bb, off);
    }
    if (lane == 0) { s[wid] = a; if (two) t[wid] = bb; }
}

// ---------- GATE layer: wave per dst node, 2-edge batch, double-buffered ----------
// ea rows loaded as VGPR uniform-address float4s (vmcnt domain) so the shuffle
// reduction's lgkmcnt waits never collide with in-flight edge-attr loads.
// Next batch's u+ea are issued before current batch's compute chain.
#define GDOT(acc, A0, A1, A2, A3) \
    acc = fmaf(A0.x, w2[0], acc);  acc = fmaf(A0.y, w2[1], acc);  \
    acc = fmaf(A0.z, w2[2], acc);  acc = fmaf(A0.w, w2[3], acc);  \
    acc = fmaf(A1.x, w2[4], acc);  acc = fmaf(A1.y, w2[5], acc);  \
    acc = fmaf(A1.z, w2[6], acc);  acc = fmaf(A1.w, w2[7], acc);  \
    acc = fmaf(A2.x, w2[8], acc);  acc = fmaf(A2.y, w2[9], acc);  \
    acc = fmaf(A2.z, w2[10], acc); acc = fmaf(A2.w, w2[11], acc); \
    acc = fmaf(A3.x, w2[12], acc); acc = fmaf(A3.y, w2[13], acc); \
    acc = fmaf(A3.z, w2[14], acc); acc = fmaf(A3.w, w2[15], acc);

__global__ __launch_bounds__(256, 4) void k_gate_gather(
    const float* __restrict__ u, const float* __restrict__ ea,
    const int* __restrict__ row, const int* __restrict__ csrc, const int* __restrict__ ceid,
    const float* __restrict__ wnl,
    const float* __restrict__ gaw, const float* __restrict__ gab,
    const float* __restrict__ sarr, float* __restrict__ Agg, int N_)
{
    int wid = (blockIdx.x * 256 + threadIdx.x) >> 6;
    int lane = threadIdx.x & 63;
    if (wid >= N_) return;
    float w2[16];
    #pragma unroll
    for (int k = 0; k < 16; ++k) w2[k] = wnl[lane * 80 + 64 + k];
    float g2 = gaw[64 + lane];
    float gb = gab[0];
    float sdst = sarr[wid];
    int beg = row[wid], end = row[wid + 1];
    float m = -INFINITY, d = 0.f, S = 0.f;
    for (int cs = beg; cs < end; cs += 64) {
        int cnt = min(64, end - cs);
        int src_l = 0, eid_l = 0;
        if (lane < cnt) { src_l = csrc[cs + lane]; eid_l = ceid[cs + lane]; }
        int cnt2 = (cnt + 1) & ~1;
        // prefetch batch 0 (edges 0,1); padded slot duplicates edge 0
        int j1 = (1 < cnt) ? 1 : 0;
        int s0 = bcasti(src_l, 0), s1 = bcasti(src_l, j1);
        int e0 = bcasti(eid_l, 0), e1 = bcasti(eid_l, j1);
        float u0 = u[(size_t)s0 * 64 + lane];
        float u1 = u[(size_t)s1 * 64 + lane];
        const float4* p0 = (const float4*)(ea + (size_t)e0 * 16);
        const float4* p1 = (const float4*)(ea + (size_t)e1 * 16);
        float4 a00 = p0[0], a01 = p0[1], a02 = p0[2], a03 = p0[3];
        float4 a10 = p1[0], a11 = p1[1], a12 = p1[2], a13 = p1[3];
        for (int l = 0; l < cnt2; l += 2) {
            // issue next batch's loads before current batch's compute chain
            int ln0 = (l + 2 < cnt) ? l + 2 : l;
            int ln1 = (l + 3 < cnt) ? l + 3 : l;
            int ns0 = bcasti(src_l, ln0), ns1 = bcasti(src_l, ln1);
            int ne0 = bcasti(eid_l, ln0), ne1 = bcasti(eid_l, ln1);
            float nu0 = u[(size_t)ns0 * 64 + lane];
            float nu1 = u[(size_t)ns1 * 64 + lane];
            const float4* q0 = (const float4*)(ea + (size_t)ne0 * 16);
            const float4* q1 = (const float4*)(ea + (size_t)ne1 * 16);
            float4 b00 = q0[0], b01 = q0[1], b02 = q0[2], b03 = q0[3];
            float4 b10 = q1[0], b11 = q1[1], b12 = q1[2], b13 = q1[3];
            // compute current batch
            float acc0 = u0, acc1 = u1;
            GDOT(acc0, a00, a01, a02, a03)
            GDOT(acc1, a10, a11, a12, a13)
            float xj0 = leaky(acc0), xj1 = leaky(acc1);
            float t0 = xj0 * g2, t1 = xj1 * g2;
            #pragma unroll
            for (int off = 32; off; off >>= 1) {
                t0 += __shfl_xor(t0, off);
                t1 += __shfl_xor(t1, off);
            }
            float sc0 = leaky(sdst + t0 + gb);
            float sc1 = (l + 1 < cnt) ? leaky(sdst + t1 + gb) : -INFINITY;
            float mn = fmaxf(m, fmaxf(sc0, sc1));
            float c = __expf(m - mn);
            float q0e = __expf(sc0 - mn), q1e = __expf(sc1 - mn);
            S = S * c;
            S = fmaf(q0e, xj0, S); S = fmaf(q1e, xj1, S);
            d = d * c + (q0e + q1e);
            m = mn;
            u0 = nu0; u1 = nu1;
            a00 = b00; a01 = b01; a02 = b02; a03 = b03;
            a10 = b10; a11 = b11; a12 = b12; a13 = b13;
        }
    }
    Agg[(size_t)wid * 64 + lane] = S / (d + 1e-16f);
}

// ---------- GAT layer: wave per dst node, pipelined weighted gather ----------
// row-value loads are issued BEFORE the score gather/reduction chain so the
// random-row latency overlaps the score phase.
__global__ __launch_bounds__(256) void k_gat_gather(
    const int* __restrict__ row, const int* __restrict__ csrc,
    const float* __restrict__ x, const float* __restrict__ sarr,
    const float* __restrict__ tarr, const float* __restrict__ cb,
    float* __restrict__ Agg, int N_)
{
    int wid = (blockIdx.x * 256 + threadIdx.x) >> 6;
    int lane = threadIdx.x & 63;
    if (wid >= N_) return;
    float sdst = sarr[wid];
    float cbv = cb[0];
    int beg = row[wid], end = row[wid + 1];
    float m = -INFINITY, d = 0.f, S = 0.f;
    for (int cs = beg; cs < end; cs += 64) {
        int cnt = min(64, end - cs);
        int src_l = 0;
        if (lane < cnt) src_l = csrc[cs + lane];
        // issue first row-group loads before the score chain
        int s0 = bcasti(src_l, 0), s1 = bcasti(src_l, 1);
        int s2 = bcasti(src_l, 2), s3 = bcasti(src_l, 3);
        float r0 = x[(size_t)s0 * 64 + lane];
        float r1 = x[(size_t)s1 * 64 + lane];
        float r2 = x[(size_t)s2 * 64 + lane];
        float r3 = x[(size_t)s3 * 64 + lane];
        float sc_l = -INFINITY;
        if (lane < cnt) sc_l = leaky(sdst + tarr[src_l] + cbv);
        float cmax = wredmax(sc_l);
        float mn = fmaxf(m, cmax);
        float c = __expf(m - mn);
        float w_l = __expf(sc_l - mn);   // 0 for lanes >= cnt
        d = d * c + wredsum(w_l);
        S *= c;
        // rows in groups of 4, one group prefetched ahead; lanes >= cnt have
        // w_l = 0 so rounding cnt up to x4 adds harmless zero-weight rows.
        int cnt4 = (cnt + 3) & ~3;
        for (int l = 0; l < cnt4; l += 4) {
            int ln = (l + 4 < cnt4) ? l + 4 : 0;
            int t0 = bcasti(src_l, ln),     t1 = bcasti(src_l, ln + 1);
            int t2 = bcasti(src_l, ln + 2), t3 = bcasti(src_l, ln + 3);
            float p0 = x[(size_t)t0 * 64 + lane];
            float p1 = x[(size_t)t1 * 64 + lane];
            float p2 = x[(size_t)t2 * 64 + lane];
            float p3 = x[(size_t)t3 * 64 + lane];
            float w0 = bcastf(w_l, l),     w1 = bcastf(w_l, l + 1);
            float w2 = bcastf(w_l, l + 2), w3 = bcastf(w_l, l + 3);
            S = fmaf(w0, r0, S); S = fmaf(w1, r1, S);
            S = fmaf(w2, r2, S); S = fmaf(w3, r3, S);
            r0 = p0; r1 = p1; r2 = p2; r3 = p3;
        }
        m = mn;
    }
    Agg[(size_t)wid * 64 + lane] = S / (d + 1e-16f);
}

// ---------- fused node update: 128-row tile, 2 rows/lane ----------
// Each weight fetched per wave now feeds 2 FMAs (rows n and n+64), halving
// scalar-cache pressure vs the 64-row version and doubling work per barrier.
__global__ __launch_bounds__(512, 4) void k_node_update(
    const float* __restrict__ agg, const float* __restrict__ xold,
    const float* __restrict__ wa, const float* __restrict__ ba,
    const float* __restrict__ wih, const float* __restrict__ whh,
    const float* __restrict__ bih, const float* __restrict__ bhh,
    float* __restrict__ xout, int M,
    const float* __restrict__ dwa, const float* __restrict__ dwb,
    float* __restrict__ sout, float* __restrict__ tout)
{
    __shared__ float tA[128 * NPAD];   // agg tile, then h tile, then out tile
    __shared__ float tX[128 * NPAD];   // xold tile; tail reused for dot partials
    int r0 = blockIdx.x * 128;
    // ---- load tiles: float4 global reads, scalar LDS writes (2-way bank = free) ----
    for (int j = threadIdx.x; j < 2048; j += 512) {
        int r = j >> 4, c4 = (j & 15) << 2; int gr = r0 + r;
        float4 av = make_float4(0.f, 0.f, 0.f, 0.f), xv = av;
        if (gr < M) {
            av = *(const float4*)(agg  + (size_t)gr * 64 + c4);
            xv = *(const float4*)(xold + (size_t)gr * 64 + c4);
        }
        int b = r * NPAD + c4;
        tA[b] = av.x; tA[b + 1] = av.y; tA[b + 2] = av.z; tA[b + 3] = av.w;
        tX[b] = xv.x; tX[b + 1] = xv.y; tX[b + 2] = xv.z; tX[b + 3] = xv.w;
    }
    __syncthreads();
    int n = threadIdx.x & 63;
    int jl = __builtin_amdgcn_readfirstlane((threadIdx.x >> 6) << 3);  // 0..56

    // Phase B: h[jl..jl+8) = elu(Agg @ Wa^T + ba), rows n and n+64
    float hvA[8], hvB[8];
    {
        float accA[8], accB[8];
        #pragma unroll
        for (int jj = 0; jj < 8; ++jj) { float bv = ba[jl + jj]; accA[jj] = bv; accB[jj] = bv; }
        for (int kc = 0; kc < 64; kc += 16) {
            float aA[16], aB[16];
            #pragma unroll
            for (int i = 0; i < 16; ++i) {
                aA[i] = tA[n * NPAD + kc + i];
                aB[i] = tA[(n + 64) * NPAD + kc + i];
            }
            #pragma unroll
            for (int jj = 0; jj < 8; ++jj) {
                const float* wr = wa + (jl + jj) * 64 + kc;
                #pragma unroll
                for (int i = 0; i < 16; ++i) {
                    float wv = wr[i];
                    accA[jj] = fmaf(wv, aA[i], accA[jj]);
                    accB[jj] = fmaf(wv, aB[i], accB[jj]);
                }
            }
        }
        #pragma unroll
        for (int jj = 0; jj < 8; ++jj) { hvA[jj] = eluf(accA[jj]); hvB[jj] = eluf(accB[jj]); }
    }
    __syncthreads();          // all phase-B reads of tA done
    #pragma unroll
    for (int jj = 0; jj < 8; ++jj) {
        tA[n * NPAD + jl + jj] = hvA[jj];
        tA[(n + 64) * NPAD + jl + jj] = hvB[jj];
    }
    __syncthreads();          // h tile visible

    // Phase C: GRU. r/z accumulate input+hidden streams; 2 rows share weights.
    float rAc[8], rBc[8], zAc[8], zBc[8], nAc[8], nBc[8], hAc[8], hBc[8];
    #pragma unroll
    for (int jj = 0; jj < 8; ++jj) {
        float brz = bih[jl + jj] + bhh[jl + jj];
        float bz  = bih[64 + jl + jj] + bhh[64 + jl + jj];
        rAc[jj] = brz; rBc[jj] = brz;
        zAc[jj] = bz;  zBc[jj] = bz;
        nAc[jj] = bih[128 + jl + jj]; nBc[jj] = nAc[jj];
        hAc[jj] = bhh[128 + jl + jj]; hBc[jj] = hAc[jj];
    }
    for (int kc = 0; kc < 64; kc += 8) {
        float h0[8], h1[8], x0[8], x1[8];
        #pragma unroll
        for (int i = 0; i < 8; ++i) {
            h0[i] = tA[n * NPAD + kc + i];
            h1[i] = tA[(n + 64) * NPAD + kc + i];
            x0[i] = tX[n * NPAD + kc + i];
            x1[i] = tX[(n + 64) * NPAD + kc + i];
        }
        #pragma unroll
        for (int jj = 0; jj < 8; ++jj) {
            const float* w1 = wih + (jl + jj) * 64 + kc;          // r, input
            const float* w4 = whh + (jl + jj) * 64 + kc;          // r, hidden
            const float* w2 = wih + (64 + jl + jj) * 64 + kc;     // z, input
            const float* w5 = whh + (64 + jl + jj) * 64 + kc;     // z, hidden
            const float* w3 = wih + (128 + jl + jj) * 64 + kc;    // n, input
            const float* w6 = whh + (128 + jl + jj) * 64 + kc;    // n, hidden
            #pragma unroll
            for (int i = 0; i < 8; ++i) {
                float v1 = w1[i], v4 = w4[i], v2 = w2[i];
                float v5 = w5[i], v3 = w3[i], v6 = w6[i];
                rAc[jj] = fmaf(v1, h0[i], rAc[jj]); rAc[jj] = fmaf(v4, x0[i], rAc[jj]);
                rBc[jj] = fmaf(v1, h1[i], rBc[jj]); rBc[jj] = fmaf(v4, x1[i], rBc[jj]);
                zAc[jj] = fmaf(v2, h0[i], zAc[jj]); zAc[jj] = fmaf(v5, x0[i], zAc[jj]);
                zBc[jj] = fmaf(v2, h1[i], zBc[jj]); zBc[jj] = fmaf(v5, x1[i], zBc[jj]);
                nAc[jj] = fmaf(v3, h0[i], nAc[jj]); hAc[jj] = fmaf(v6, x0[i], hAc[jj]);
                nBc[jj] = fmaf(v3, h1[i], nBc[jj]); hBc[jj] = fmaf(v6, x1[i], hBc[jj]);
            }
        }
    }
    #pragma unroll
    for (int jj = 0; jj < 8; ++jj) {
        float r = sigm(rAc[jj]);
        float z = sigm(zAc[jj]);
        float nn = tanhfast(nAc[jj] + r * hAc[jj]);
        float xo = tX[n * NPAD + jl + jj];
        float v = (1.f - z) * nn + z * xo;
        hvA[jj] = fmaxf(v, 0.f);

        float rb = sigm(rBc[jj]);
        float zb = sigm(zBc[jj]);
        float nb_ = tanhfast(nBc[jj] + rb * hBc[jj]);
        float xob = tX[(n + 64) * NPAD + jl + jj];
        float vb = (1.f - zb) * nb_ + zb * xob;
        hvB[jj] = fmaxf(vb, 0.f);
    }
    __syncthreads();          // all phase-C reads of tA/tX done
    #pragma unroll
    for (int jj = 0; jj < 8; ++jj) {
        tA[n * NPAD + jl + jj] = hvA[jj];
        tA[(n + 64) * NPAD + jl + jj] = hvB[jj];
    }
    // Fused align dots: register partials per (row, wave) into tX (dead now),
    // reduced by 128 threads after the barrier. Replaces 16x wredsum epilogue.
    if (sout != nullptr) {
        float paA = 0.f, pbA = 0.f, paB = 0.f, pbB = 0.f;
        #pragma unroll
        for (int jj = 0; jj < 8; ++jj) {
            float wav = dwa[jl + jj], wbv = dwb[jl + jj];
            paA = fmaf(hvA[jj], wav, paA); pbA = fmaf(hvA[jj], wbv, pbA);
            paB = fmaf(hvB[jj], wav, paB); pbB = fmaf(hvB[jj], wbv, pbB);
        }
        int w2i = (threadIdx.x >> 6) << 1;              // slot 0..14
        tX[n * 17 + w2i]            = paA;
        tX[n * 17 + w2i + 1]        = pbA;
        tX[(n + 64) * 17 + w2i]     = paB;
        tX[(n + 64) * 17 + w2i + 1] = pbB;
    }
    __syncthreads();
    for (int j = threadIdx.x; j < 2048; j += 512) {
        int r = j >> 4, c4 = (j & 15) << 2; int gr = r0 + r;
        if (gr < M) {
            int b = r * NPAD + c4;
            float4 ov = make_float4(tA[b], tA[b + 1], tA[b + 2], tA[b + 3]);
            *(float4*)(xout + (size_t)gr * 64 + c4) = ov;
        }
    }
    if (sout != nullptr && threadIdx.x < 128) {
        int r = threadIdx.x; int gr = r0 + r;
        if (gr < M) {
            float sa = 0.f, sb = 0.f;
            #pragma unroll
            for (int w = 0; w < 16; w += 2) { sa += tX[r * 17 + w]; sb += tX[r * 17 + w + 1]; }
            sout[gr] = sa; tout[gr] = sb;
        }
    }
}

// ---------- readout: wave per graph, contiguous segment sum + relu ----------
__global__ __launch_bounds__(256) void k_seg_sum_relu(
    const float* __restrict__ x, const int* __restrict__ gst,
    float* __restrict__ outp, int G_)
{
    int g = (blockIdx.x * 256 + threadIdx.x) >> 6;
    int lane = threadIdx.x & 63;
    if (g >= G_) return;
    float S0 = 0.f, S1 = 0.f, S2 = 0.f, S3 = 0.f;
    int end = gst[g + 1];
    int i = gst[g];
    for (; i + 4 <= end; i += 4) {
        S0 += x[(size_t)i * 64 + lane];
        S1 += x[(size_t)(i + 1) * 64 + lane];
        S2 += x[(size_t)(i + 2) * 64 + lane];
        S3 += x[(size_t)(i + 3) * 64 + lane];
    }
    for (; i < end; ++i) S0 += x[(size_t)i * 64 + lane];
    outp[(size_t)g * 64 + lane] = fmaxf((S0 + S1) + (S2 + S3), 0.f);
}

// ---------- mol: per-node dot of mix with align part 2 ----------
__global__ __launch_bounds__(256) void k_mol_dots(
    const float* __restrict__ xf, const float* __restrict__ cach,
    const float* __restrict__ maw, float* __restrict__ dd, int n)
{
    int wid = (blockIdx.x * 256 + threadIdx.x) >> 6;
    int lane = threadIdx.x & 63;
    if (wid >= n) return;
    float mix = 0.5f * (xf[(size_t)wid * 64 + lane] + cach[(size_t)wid * 64 + lane]);
    float v = wredsum(mix * maw[64 + lane]);
    if (lane == 0) dd[wid] = v;
}

// ---------- molecule attention: wave per graph, pipelined gather ----------
// row-value loads hoisted above the score chain (same latency-overlap fix).
__global__ __launch_bounds__(256) void k_mol_gather(
    const float* __restrict__ xf, const float* __restrict__ cach,
    const float* __restrict__ stateIn, const int* __restrict__ gst,
    const float* __restrict__ dd,
    const float* __restrict__ maw, const float* __restrict__ mab,
    float* __restrict__ Agg, int G_)
{
    int g = (blockIdx.x * 256 + threadIdx.x) >> 6;
    int lane = threadIdx.x & 63;
    if (g >= G_) return;
    float o = stateIn[(size_t)g * 64 + lane];
    float og = wredsum(o * maw[lane]);
    float mb = mab[0];
    int beg = gst[g], end = gst[g + 1];
    float m = -INFINITY, d = 0.f, S = 0.f;
    for (int cs = beg; cs < end; cs += 64) {
        int cnt = min(64, end - cs);
        // issue first row-group loads before the score chain
        size_t rb = (size_t)cs * 64 + lane;
        float x0 = xf[rb],      c0 = cach[rb];
        float x1 = xf[rb + 64], c1 = cach[rb + 64];
        float x2 = xf[rb + 128], c2 = cach[rb + 128];
        float x3 = xf[rb + 192], c3 = cach[rb + 192];
        float sc_l = -INFINITY;
        if (lane < cnt) sc_l = leaky(og + dd[cs + lane] + mb);
        float cmax = wredmax(sc_l);
        float mn = fmaxf(m, cmax);
        float c = __expf(m - mn);
        float w_l = __expf(sc_l - mn);   // 0 for lanes >= cnt
        d = d * c + wredsum(w_l);
        S *= c;
        int cnt4 = (cnt + 3) & ~3;
        for (int l = 0; l < cnt4; l += 4) {
            int ln = (l + 4 < cnt4) ? l + 4 : 0;
            size_t rn = (size_t)(cs + ln) * 64 + lane;
            float y0 = xf[rn],       d0 = cach[rn];
            float y1 = xf[rn + 64],  d1 = cach[rn + 64];
            float y2 = xf[rn + 128], d2 = cach[rn + 128];
            float y3 = xf[rn + 192], d3 = cach[rn + 192];
            float w0 = bcastf(w_l, l),     w1 = bcastf(w_l, l + 1);
            float w2 = bcastf(w_l, l + 2), w3 = bcastf(w_l, l + 3);
            S = fmaf(w0, 0.5f * (x0 + c0), S);
            S = fmaf(w1, 0.5f * (x1 + c1), S);
            S = fmaf(w2, 0.5f * (x2 + c2), S);
            S = fmaf(w3, 0.5f * (x3 + c3), S);
            x0 = y0; c0 = d0; x1 = y1; c1 = d1;
            x2 = y2; c2 = d2; x3 = y3; c3 = d3;
        }
        m = mn;
    }
    Agg[(size_t)g * 64 + lane] = S / (d + 1e-16f);
}

// ---------- final: out[g] = state[g].lin2_w + lin2_b ----------
__global__ __launch_bounds__(256) void k_lin2(
    const float* __restrict__ st, const float* __restrict__ w,
    const float* __restrict__ b, float* __restrict__ outp, int g)
{
    int gt = blockIdx.x * 256 + threadIdx.x;
    int wid = gt >> 6, lane = threadIdx.x & 63;
    if (wid >= g) return;
    float v = st[(size_t)wid * 64 + lane] * w[lane];
    #pragma unroll
    for (int off = 32; off; off >>= 1) v += __shfl_down(v, off);
    if (lane == 0) outp[wid] = v + b[0];
}

// =====================================================================
extern "C" void kernel_launch(void* const* d_in, const int* in_sizes, int n_in,
                              void* d_out, int out_size, void* d_ws, size_t ws_size,
                              hipStream_t stream) {
    const float* raw           = (const float*)d_in[0];
    const int*   ei            = (const int*)d_in[1];
    const float* ea            = (const float*)d_in[2];
    const int*   batch         = (const int*)d_in[3];
    const float* lin1_w        = (const float*)d_in[4];
    const float* lin1_b        = (const float*)d_in[5];
    const float* gate_nl_w     = (const float*)d_in[6];
    const float* gate_nl_b     = (const float*)d_in[7];
    const float* gate_align_w  = (const float*)d_in[8];
    const float* gate_align_b  = (const float*)d_in[9];
    const float* gate_attend_w = (const float*)d_in[10];
    const float* gate_attend_b = (const float*)d_in[11];
    const float* conv_align_w  = (const float*)d_in[12];
    const float* conv_align_b  = (const float*)d_in[13];
    const float* conv_attend_w = (const float*)d_in[14];
    const float* conv_attend_b = (const float*)d_in[15];
    const float* gru_wih       = (const float*)d_in[16];
    const float* gru_whh       = (const float*)d_in[17];
    const float* gru_bih       = (const float*)d_in[18];
    const float* gru_bhh       = (const float*)d_in[19];
    const float* mol_align_w   = (const float*)d_in[20];
    const float* mol_align_b   = (const float*)d_in[21];
    const float* mol_attend_w  = (const float*)d_in[22];
    const float* mol_attend_b  = (const float*)d_in[23];
    const float* mol_wih       = (const float*)d_in[24];
    const float* mol_whh       = (const float*)d_in[25];
    const float* mol_bih       = (const float*)d_in[26];
    const float* mol_bhh       = (const float*)d_in[27];
    const float* lin2_w        = (const float*)d_in[28];
    const float* lin2_b        = (const float*)d_in[29];
    float* out = (float*)d_out;

    const int N = in_sizes[3];
    const int E = in_sizes[1] / 2;
    const int G = out_size;
    const size_t N64 = (size_t)N * 64;
    const size_t G64 = (size_t)G * 64;

    // ---- workspace layout ----
    float* f = (float*)d_ws;
    float* xA    = f;
    float* xB    = xA + N64;
    float* xD    = xB + N64;
    float* Agg   = xD + N64;
    float* u     = Agg + N64;
    float* sN    = u + N64;
    float* tN    = sN + N;
    float* dd    = tN + N;
    float* outS  = dd + N;
    float* outS2 = outS + G64;
    float* aggG  = outS2 + G64;
    int* row  = (int*)(aggG + G64);
    int* csrc = row + (N + 1);
    int* ceid = csrc + E;
    int* bsum = ceid + E;
    int* gst  = bsum + 512;
    int* deg = (int*)Agg;
    int* cur = deg + N;

    const int nb_node64  = (N + 63) / 64;
    const int nb_node128 = (N + 127) / 128;
    const int nb_edge   = (E + 255) / 256;
    const int nb_nodes  = (N + 255) / 256;
    const int nb_waveN  = (N + 3) / 4;
    const int nb_waveG  = (G + 3) / 4;
    const int nb_nodeG  = (G + 127) / 128;

    // ---- CSR build ----
    hipMemsetAsync(deg, 0, (size_t)N * 4, stream);
    k_hist<<<nb_edge, 256, 0, stream>>>(ei, deg, E);
    k_scan1<<<nb_nodes, 256, 0, stream>>>(deg, bsum, N);
    k_scan2<<<1, 512, 0, stream>>>(bsum, nb_nodes);
    k_scan3<<<nb_nodes, 256, 0, stream>>>(deg, bsum, row, cur, N, E);
    k_scatter<<<nb_edge, 256, 0, stream>>>(ei, cur, csrc, ceid, E);
    k_gbounds<<<nb_nodes, 256, 0, stream>>>(batch, gst, N, G);

    // ---- lin1 + gate node-part precompute ----
    k_dense64<<<nb_node64, 256, 0, stream>>>(raw, lin1_w, 64, lin1_b, xA, N, 1);
    k_dense64<<<nb_node64, 256, 0, stream>>>(raw, gate_nl_w, 80, gate_nl_b, u, N, 0);

    // ---- layer 0: GATEConv (xA -> xB); emits align dots for GAT layer 0 ----
    k_node_dot2<<<nb_waveN, 256, 0, stream>>>(xA, gate_align_w, gate_align_w, sN, tN, N, 0);
    k_gate_gather<<<nb_waveN, 256, 0, stream>>>(u, ea, row, csrc, ceid,
                                                gate_nl_w, gate_align_w, gate_align_b,
                                                sN, Agg, N);
    k_node_update<<<nb_node128, 512, 0, stream>>>(Agg, xA, gate_attend_w, gate_attend_b,
                                                  gru_wih, gru_whh, gru_bih, gru_bhh, xB, N,
                                                  conv_align_w, conv_align_w + 64, sN, tN);

    // ---- GAT layer 0 (xB -> xD); emits align dots for GAT layer 1 ----
    k_gat_gather<<<nb_waveN, 256, 0, stream>>>(row, csrc, xB, sN, tN, conv_align_b, Agg, N);
    k_node_update<<<nb_node128, 512, 0, stream>>>(Agg, xB, conv_attend_w, conv_attend_b,
                                                  gru_wih + 12288, gru_whh + 12288,
                                                  gru_bih + 192, gru_bhh + 192, xD, N,
                                                  conv_align_w + 128, conv_align_w + 192, sN, tN);

    // ---- GAT layer 1 (xD -> xA) ----
    k_gat_gather<<<nb_waveN, 256, 0, stream>>>(row, csrc, xD, sN, tN, conv_align_b + 1, Agg, N);
    k_node_update<<<nb_node128, 512, 0, stream>>>(Agg, xD, conv_attend_w + 4096, conv_attend_b + 64,
                                                  gru_wih + 24576, gru_whh + 24576,
                                                  gru_bih + 384, gru_bhh + 384, xA, N,
                                                  nullptr, nullptr, nullptr, nullptr);

    // ---- molecule readout ----
    k_seg_sum_relu<<<nb_waveG, 256, 0, stream>>>(xA, gst, outS, G);

    const float* cachedP[2] = { xD, xA };
    float* sIn = outS; float* sOut = outS2;
    for (int t = 0; t < 2; ++t) {
        k_mol_dots<<<nb_waveN, 256, 0, stream>>>(xA, cachedP[t], mol_align_w, dd, N);
        k_mol_gather<<<nb_waveG, 256, 0, stream>>>(xA, cachedP[t], sIn, gst, dd,
                                                   mol_align_w, mol_align_b, aggG, G);
        k_node_update<<<nb_nodeG, 512, 0, stream>>>(aggG, sIn, mol_attend_w, mol_attend_b,
                                                    mol_wih, mol_whh, mol_bih, mol_bhh, sOut, G,
                                                    nullptr, nullptr, nullptr, nullptr);
        float* tmp = sIn; sIn = sOut; sOut = tmp;
    }

    k_lin2<<<nb_waveG, 256, 0, stream>>>(sIn, lin2_w, lin2_b, out, G);
}

// Round 4
// 1071.279 us; speedup vs baseline: 1.4506x; 1.0187x over previous
//
#include <hip/hip_runtime.h>
#include <math.h>

#define NPAD 65

// ---------- small device helpers ----------
__device__ __forceinline__ float leaky(float x) { return x > 0.f ? x : 0.01f * x; }
__device__ __forceinline__ float eluf(float x)  { return x > 0.f ? x : (__expf(x) - 1.f); }
__device__ __forceinline__ float sigm(float x)  { return 1.f / (1.f + __expf(-x)); }
__device__ __forceinline__ float tanhfast(float x) { return 1.f - 2.f / (__expf(2.f * x) + 1.f); }

__device__ __forceinline__ float bcastf(float v, int k) {
    return __uint_as_float((unsigned)__builtin_amdgcn_readlane((int)__float_as_uint(v), k));
}
__device__ __forceinline__ int bcasti(int v, int k) {
    return __builtin_amdgcn_readlane(v, k);
}
__device__ __forceinline__ float wredsum(float v) {
    #pragma unroll
    for (int off = 32; off; off >>= 1) v += __shfl_xor(v, off);
    return v;
}
__device__ __forceinline__ float wredmax(float v) {
    #pragma unroll
    for (int off = 32; off; off >>= 1) v = fmaxf(v, __shfl_xor(v, off));
    return v;
}

// ================= CSR build =================
__global__ __launch_bounds__(256) void k_hist(const int* __restrict__ ei, int* __restrict__ deg, int E_) {
    int e = blockIdx.x * 256 + threadIdx.x;
    if (e < E_) atomicAdd(&deg[ei[E_ + e]], 1);
}

__global__ __launch_bounds__(256) void k_scan1(const int* __restrict__ deg, int* __restrict__ bsum, int N_) {
    __shared__ int s[256];
    int i = blockIdx.x * 256 + threadIdx.x;
    s[threadIdx.x] = (i < N_) ? deg[i] : 0;
    __syncthreads();
    for (int off = 128; off; off >>= 1) {
        if (threadIdx.x < off) s[threadIdx.x] += s[threadIdx.x + off];
        __syncthreads();
    }
    if (threadIdx.x == 0) bsum[blockIdx.x] = s[0];
}

// parallel exclusive scan of block sums (single block, chunked w/ carry)
__global__ __launch_bounds__(512) void k_scan2(int* __restrict__ bsum, int nb) {
    __shared__ int s[512];
    __shared__ int carry_s;
    if (threadIdx.x == 0) carry_s = 0;
    __syncthreads();
    for (int base = 0; base < nb; base += 512) {
        int t = threadIdx.x;
        int idx = base + t;
        int v = (idx < nb) ? bsum[idx] : 0;
        s[t] = v;
        __syncthreads();
        #pragma unroll
        for (int off = 1; off < 512; off <<= 1) {
            int u = (t >= off) ? s[t - off] : 0;
            __syncthreads();
            s[t] += u;
            __syncthreads();
        }
        int carry = carry_s;
        if (idx < nb) bsum[idx] = carry + s[t] - v;   // exclusive
        __syncthreads();
        if (t == 0) carry_s = carry + s[511];
        __syncthreads();
    }
}

__global__ __launch_bounds__(256) void k_scan3(const int* __restrict__ deg, const int* __restrict__ bsum,
                                               int* __restrict__ row, int* __restrict__ cur, int N_, int E_) {
    __shared__ int s[256];
    int i = blockIdx.x * 256 + threadIdx.x;
    int d = (i < N_) ? deg[i] : 0;
    s[threadIdx.x] = d;
    __syncthreads();
    for (int off = 1; off < 256; off <<= 1) {
        int v = (threadIdx.x >= off) ? s[threadIdx.x - off] : 0;
        __syncthreads();
        s[threadIdx.x] += v;
        __syncthreads();
    }
    if (i < N_) {
        int ex = bsum[blockIdx.x] + s[threadIdx.x] - d;
        row[i] = ex; cur[i] = ex;
    }
    if (i == N_ - 1) row[N_] = E_;
}

__global__ __launch_bounds__(256) void k_scatter(const int* __restrict__ ei, int* __restrict__ cur,
                                                 int* __restrict__ csrc, int* __restrict__ ceid, int E_) {
    int e = blockIdx.x * 256 + threadIdx.x;
    if (e >= E_) return;
    int dst = ei[E_ + e];
    int slot = atomicAdd(&cur[dst], 1);
    csrc[slot] = ei[e];
    ceid[slot] = e;
}

__global__ __launch_bounds__(256) void k_gbounds(const int* __restrict__ batch, int* __restrict__ gst,
                                                 int N_, int G_) {
    int i = blockIdx.x * 256 + threadIdx.x;
    if (i >= N_) return;
    int b = batch[i];
    int prev = (i == 0) ? -1 : batch[i - 1];
    for (int g = prev + 1; g <= b; ++g) gst[g] = i;
    if (i == N_ - 1) { for (int g = b + 1; g <= G_; ++g) gst[g] = N_; }
}

// ---------- dense64: out = act(in @ w^T + b); optional fused per-row dot ----------
// dsout[r] = dot(out_row_r, dva) computed from the LDS 'to' tile (kills the
// separate k_node_dot2 launch over 100k waves).
__global__ __launch_bounds__(256) void k_dense64(
    const float* __restrict__ in, const float* __restrict__ w, int wstride,
    const float* __restrict__ b, float* __restrict__ outp, int M, int act,
    const float* __restrict__ dva, float* __restrict__ dsout)
{
    __shared__ float ti[64 * NPAD];
    __shared__ float to[64 * NPAD];
    int r0 = blockIdx.x * 64;
    for (int i = threadIdx.x; i < 4096; i += 256) {
        int r = i >> 6, c = i & 63; int gr = r0 + r;
        ti[r * NPAD + c] = (gr < M) ? in[(size_t)gr * 64 + c] : 0.f;
    }
    __syncthreads();
    int n = threadIdx.x & 63;
    int jl = __builtin_amdgcn_readfirstlane((threadIdx.x >> 6) << 4);
    float acc[16];
    #pragma unroll
    for (int jj = 0; jj < 16; ++jj) acc[jj] = b[jl + jj];
    for (int kc = 0; kc < 64; kc += 16) {
        float xr[16];
        #pragma unroll
        for (int i = 0; i < 16; ++i) xr[i] = ti[n * NPAD + kc + i];
        #pragma unroll
        for (int jj = 0; jj < 16; ++jj) {
            const float* wr = w + (jl + jj) * wstride + kc;
            #pragma unroll
            for (int i = 0; i < 16; ++i) acc[jj] = fmaf(wr[i], xr[i], acc[jj]);
        }
    }
    #pragma unroll
    for (int jj = 0; jj < 16; ++jj) {
        float v = acc[jj];
        to[n * NPAD + jl + jj] = act ? leaky(v) : v;
    }
    __syncthreads();
    for (int i = threadIdx.x; i < 4096; i += 256) {
        int r = i >> 6, c = i & 63; int gr = r0 + r;
        if (gr < M) outp[(size_t)gr * 64 + c] = to[r * NPAD + c];
    }
    if (dsout != nullptr) {
        int wv = threadIdx.x >> 6;          // 0..3, handles rows wv*16..wv*16+15
        float wval = dva[n];
        #pragma unroll 4
        for (int q = 0; q < 16; ++q) {
            int r = (wv << 4) + q; int gr = r0 + r;
            float pv = wredsum(to[r * NPAD + n] * wval);
            if (n == 0 && gr < M) dsout[gr] = pv;
        }
    }
}

// ---------- GATE layer: wave per dst node, 2-edge batch, double-buffered ----------
#define GDOT(acc, A0, A1, A2, A3) \
    acc = fmaf(A0.x, w2[0], acc);  acc = fmaf(A0.y, w2[1], acc);  \
    acc = fmaf(A0.z, w2[2], acc);  acc = fmaf(A0.w, w2[3], acc);  \
    acc = fmaf(A1.x, w2[4], acc);  acc = fmaf(A1.y, w2[5], acc);  \
    acc = fmaf(A1.z, w2[6], acc);  acc = fmaf(A1.w, w2[7], acc);  \
    acc = fmaf(A2.x, w2[8], acc);  acc = fmaf(A2.y, w2[9], acc);  \
    acc = fmaf(A2.z, w2[10], acc); acc = fmaf(A2.w, w2[11], acc); \
    acc = fmaf(A3.x, w2[12], acc); acc = fmaf(A3.y, w2[13], acc); \
    acc = fmaf(A3.z, w2[14], acc); acc = fmaf(A3.w, w2[15], acc);

__global__ __launch_bounds__(256, 4) void k_gate_gather(
    const float* __restrict__ u, const float* __restrict__ ea,
    const int* __restrict__ row, const int* __restrict__ csrc, const int* __restrict__ ceid,
    const float* __restrict__ wnl,
    const float* __restrict__ gaw, const float* __restrict__ gab,
    const float* __restrict__ sarr, float* __restrict__ Agg, int N_)
{
    int wid = (blockIdx.x * 256 + threadIdx.x) >> 6;
    int lane = threadIdx.x & 63;
    if (wid >= N_) return;
    float w2[16];
    #pragma unroll
    for (int k = 0; k < 16; ++k) w2[k] = wnl[lane * 80 + 64 + k];
    float g2 = gaw[64 + lane];
    float gb = gab[0];
    float sdst = sarr[wid];
    int beg = row[wid], end = row[wid + 1];
    float m = -INFINITY, d = 0.f, S = 0.f;
    for (int cs = beg; cs < end; cs += 64) {
        int cnt = min(64, end - cs);
        int src_l = 0, eid_l = 0;
        if (lane < cnt) { src_l = csrc[cs + lane]; eid_l = ceid[cs + lane]; }
        int cnt2 = (cnt + 1) & ~1;
        // prefetch batch 0 (edges 0,1); padded slot duplicates edge 0
        int j1 = (1 < cnt) ? 1 : 0;
        int s0 = bcasti(src_l, 0), s1 = bcasti(src_l, j1);
        int e0 = bcasti(eid_l, 0), e1 = bcasti(eid_l, j1);
        float u0 = u[(size_t)s0 * 64 + lane];
        float u1 = u[(size_t)s1 * 64 + lane];
        const float4* p0 = (const float4*)(ea + (size_t)e0 * 16);
        const float4* p1 = (const float4*)(ea + (size_t)e1 * 16);
        float4 a00 = p0[0], a01 = p0[1], a02 = p0[2], a03 = p0[3];
        float4 a10 = p1[0], a11 = p1[1], a12 = p1[2], a13 = p1[3];
        for (int l = 0; l < cnt2; l += 2) {
            // issue next batch's loads before current batch's compute chain
            int ln0 = (l + 2 < cnt) ? l + 2 : l;
            int ln1 = (l + 3 < cnt) ? l + 3 : l;
            int ns0 = bcasti(src_l, ln0), ns1 = bcasti(src_l, ln1);
            int ne0 = bcasti(eid_l, ln0), ne1 = bcasti(eid_l, ln1);
            float nu0 = u[(size_t)ns0 * 64 + lane];
            float nu1 = u[(size_t)ns1 * 64 + lane];
            const float4* q0 = (const float4*)(ea + (size_t)ne0 * 16);
            const float4* q1 = (const float4*)(ea + (size_t)ne1 * 16);
            float4 b00 = q0[0], b01 = q0[1], b02 = q0[2], b03 = q0[3];
            float4 b10 = q1[0], b11 = q1[1], b12 = q1[2], b13 = q1[3];
            // compute current batch
            float acc0 = u0, acc1 = u1;
            GDOT(acc0, a00, a01, a02, a03)
            GDOT(acc1, a10, a11, a12, a13)
            float xj0 = leaky(acc0), xj1 = leaky(acc1);
            float t0 = xj0 * g2, t1 = xj1 * g2;
            #pragma unroll
            for (int off = 32; off; off >>= 1) {
                t0 += __shfl_xor(t0, off);
                t1 += __shfl_xor(t1, off);
            }
            float sc0 = leaky(sdst + t0 + gb);
            float sc1 = (l + 1 < cnt) ? leaky(sdst + t1 + gb) : -INFINITY;
            float mn = fmaxf(m, fmaxf(sc0, sc1));
            float c = __expf(m - mn);
            float q0e = __expf(sc0 - mn), q1e = __expf(sc1 - mn);
            S = S * c;
            S = fmaf(q0e, xj0, S); S = fmaf(q1e, xj1, S);
            d = d * c + (q0e + q1e);
            m = mn;
            u0 = nu0; u1 = nu1;
            a00 = b00; a01 = b01; a02 = b02; a03 = b03;
            a10 = b10; a11 = b11; a12 = b12; a13 = b13;
        }
    }
    Agg[(size_t)wid * 64 + lane] = S / (d + 1e-16f);
}

// ---------- GAT layer: wave per dst node, pipelined weighted gather ----------
__global__ __launch_bounds__(256) void k_gat_gather(
    const int* __restrict__ row, const int* __restrict__ csrc,
    const float* __restrict__ x, const float* __restrict__ sarr,
    const float* __restrict__ tarr, const float* __restrict__ cb,
    float* __restrict__ Agg, int N_)
{
    int wid = (blockIdx.x * 256 + threadIdx.x) >> 6;
    int lane = threadIdx.x & 63;
    if (wid >= N_) return;
    float sdst = sarr[wid];
    float cbv = cb[0];
    int beg = row[wid], end = row[wid + 1];
    float m = -INFINITY, d = 0.f, S = 0.f;
    for (int cs = beg; cs < end; cs += 64) {
        int cnt = min(64, end - cs);
        int src_l = 0;
        if (lane < cnt) src_l = csrc[cs + lane];
        // issue first row-group loads before the score chain
        int s0 = bcasti(src_l, 0), s1 = bcasti(src_l, 1);
        int s2 = bcasti(src_l, 2), s3 = bcasti(src_l, 3);
        float r0 = x[(size_t)s0 * 64 + lane];
        float r1 = x[(size_t)s1 * 64 + lane];
        float r2 = x[(size_t)s2 * 64 + lane];
        float r3 = x[(size_t)s3 * 64 + lane];
        float sc_l = -INFINITY;
        if (lane < cnt) sc_l = leaky(sdst + tarr[src_l] + cbv);
        float cmax = wredmax(sc_l);
        float mn = fmaxf(m, cmax);
        float c = __expf(m - mn);
        float w_l = __expf(sc_l - mn);   // 0 for lanes >= cnt
        d = d * c + wredsum(w_l);
        S *= c;
        int cnt4 = (cnt + 3) & ~3;
        for (int l = 0; l < cnt4; l += 4) {
            int ln = (l + 4 < cnt4) ? l + 4 : 0;
            int t0 = bcasti(src_l, ln),     t1 = bcasti(src_l, ln + 1);
            int t2 = bcasti(src_l, ln + 2), t3 = bcasti(src_l, ln + 3);
            float p0 = x[(size_t)t0 * 64 + lane];
            float p1 = x[(size_t)t1 * 64 + lane];
            float p2 = x[(size_t)t2 * 64 + lane];
            float p3 = x[(size_t)t3 * 64 + lane];
            float w0 = bcastf(w_l, l),     w1 = bcastf(w_l, l + 1);
            float w2 = bcastf(w_l, l + 2), w3 = bcastf(w_l, l + 3);
            S = fmaf(w0, r0, S); S = fmaf(w1, r1, S);
            S = fmaf(w2, r2, S); S = fmaf(w3, r3, S);
            r0 = p0; r1 = p1; r2 = p2; r3 = p3;
        }
        m = mn;
    }
    Agg[(size_t)wid * 64 + lane] = S / (d + 1e-16f);
}

// ---------- fused node update: 128-row tile, 2 rows/lane ----------
// mode 0: sout=dot(hv,dwa), tout=dot(hv,dwb)           (align dots, next layer)
// mode 1: sout=dot(0.5(hv+xold),dwa), tout=dot(hv,dwa) (mol dd0/dd1, kills k_mol_dots)
// mode 2: sout=dot(hv,dwa)+dwb[0]                      (final lin2, kills k_lin2)
__global__ __launch_bounds__(512, 4) void k_node_update(
    const float* __restrict__ agg, const float* __restrict__ xold,
    const float* __restrict__ wa, const float* __restrict__ ba,
    const float* __restrict__ wih, const float* __restrict__ whh,
    const float* __restrict__ bih, const float* __restrict__ bhh,
    float* __restrict__ xout, int M,
    const float* __restrict__ dwa, const float* __restrict__ dwb,
    float* __restrict__ sout, float* __restrict__ tout, int mode)
{
    __shared__ float tA[128 * NPAD];   // agg tile, then h tile, then out tile
    __shared__ float tX[128 * NPAD];   // xold tile; head reused for dot partials
    int r0 = blockIdx.x * 128;
    for (int j = threadIdx.x; j < 2048; j += 512) {
        int r = j >> 4, c4 = (j & 15) << 2; int gr = r0 + r;
        float4 av = make_float4(0.f, 0.f, 0.f, 0.f), xv = av;
        if (gr < M) {
            av = *(const float4*)(agg  + (size_t)gr * 64 + c4);
            xv = *(const float4*)(xold + (size_t)gr * 64 + c4);
        }
        int b = r * NPAD + c4;
        tA[b] = av.x; tA[b + 1] = av.y; tA[b + 2] = av.z; tA[b + 3] = av.w;
        tX[b] = xv.x; tX[b + 1] = xv.y; tX[b + 2] = xv.z; tX[b + 3] = xv.w;
    }
    __syncthreads();
    int n = threadIdx.x & 63;
    int jl = __builtin_amdgcn_readfirstlane((threadIdx.x >> 6) << 3);  // 0..56

    // Phase B: h[jl..jl+8) = elu(Agg @ Wa^T + ba), rows n and n+64
    float hvA[8], hvB[8];
    {
        float accA[8], accB[8];
        #pragma unroll
        for (int jj = 0; jj < 8; ++jj) { float bv = ba[jl + jj]; accA[jj] = bv; accB[jj] = bv; }
        for (int kc = 0; kc < 64; kc += 16) {
            float aA[16], aB[16];
            #pragma unroll
            for (int i = 0; i < 16; ++i) {
                aA[i] = tA[n * NPAD + kc + i];
                aB[i] = tA[(n + 64) * NPAD + kc + i];
            }
            #pragma unroll
            for (int jj = 0; jj < 8; ++jj) {
                const float* wr = wa + (jl + jj) * 64 + kc;
                #pragma unroll
                for (int i = 0; i < 16; ++i) {
                    float wv = wr[i];
                    accA[jj] = fmaf(wv, aA[i], accA[jj]);
                    accB[jj] = fmaf(wv, aB[i], accB[jj]);
                }
            }
        }
        #pragma unroll
        for (int jj = 0; jj < 8; ++jj) { hvA[jj] = eluf(accA[jj]); hvB[jj] = eluf(accB[jj]); }
    }
    __syncthreads();          // all phase-B reads of tA done
    #pragma unroll
    for (int jj = 0; jj < 8; ++jj) {
        tA[n * NPAD + jl + jj] = hvA[jj];
        tA[(n + 64) * NPAD + jl + jj] = hvB[jj];
    }
    __syncthreads();          // h tile visible

    // Phase C: GRU. r/z accumulate input+hidden streams; 2 rows share weights.
    float rAc[8], rBc[8], zAc[8], zBc[8], nAc[8], nBc[8], hAc[8], hBc[8];
    #pragma unroll
    for (int jj = 0; jj < 8; ++jj) {
        float brz = bih[jl + jj] + bhh[jl + jj];
        float bz  = bih[64 + jl + jj] + bhh[64 + jl + jj];
        rAc[jj] = brz; rBc[jj] = brz;
        zAc[jj] = bz;  zBc[jj] = bz;
        nAc[jj] = bih[128 + jl + jj]; nBc[jj] = nAc[jj];
        hAc[jj] = bhh[128 + jl + jj]; hBc[jj] = hAc[jj];
    }
    for (int kc = 0; kc < 64; kc += 8) {
        float h0[8], h1[8], x0[8], x1[8];
        #pragma unroll
        for (int i = 0; i < 8; ++i) {
            h0[i] = tA[n * NPAD + kc + i];
            h1[i] = tA[(n + 64) * NPAD + kc + i];
            x0[i] = tX[n * NPAD + kc + i];
            x1[i] = tX[(n + 64) * NPAD + kc + i];
        }
        #pragma unroll
        for (int jj = 0; jj < 8; ++jj) {
            const float* w1 = wih + (jl + jj) * 64 + kc;          // r, input
            const float* w4 = whh + (jl + jj) * 64 + kc;          // r, hidden
            const float* w2 = wih + (64 + jl + jj) * 64 + kc;     // z, input
            const float* w5 = whh + (64 + jl + jj) * 64 + kc;     // z, hidden
            const float* w3 = wih + (128 + jl + jj) * 64 + kc;    // n, input
            const float* w6 = whh + (128 + jl + jj) * 64 + kc;    // n, hidden
            #pragma unroll
            for (int i = 0; i < 8; ++i) {
                float v1 = w1[i], v4 = w4[i], v2 = w2[i];
                float v5 = w5[i], v3 = w3[i], v6 = w6[i];
                rAc[jj] = fmaf(v1, h0[i], rAc[jj]); rAc[jj] = fmaf(v4, x0[i], rAc[jj]);
                rBc[jj] = fmaf(v1, h1[i], rBc[jj]); rBc[jj] = fmaf(v4, x1[i], rBc[jj]);
                zAc[jj] = fmaf(v2, h0[i], zAc[jj]); zAc[jj] = fmaf(v5, x0[i], zAc[jj]);
                zBc[jj] = fmaf(v2, h1[i], zBc[jj]); zBc[jj] = fmaf(v5, x1[i], zBc[jj]);
                nAc[jj] = fmaf(v3, h0[i], nAc[jj]); hAc[jj] = fmaf(v6, x0[i], hAc[jj]);
                nBc[jj] = fmaf(v3, h1[i], nBc[jj]); hBc[jj] = fmaf(v6, x1[i], hBc[jj]);
            }
        }
    }
    // final activation + (optional) fused dot partials, using in-register hv/xo
    float paA = 0.f, pbA = 0.f, paB = 0.f, pbB = 0.f;
    #pragma unroll
    for (int jj = 0; jj < 8; ++jj) {
        float r = sigm(rAc[jj]);
        float z = sigm(zAc[jj]);
        float nn = tanhfast(nAc[jj] + r * hAc[jj]);
        float xo = tX[n * NPAD + jl + jj];
        float v = (1.f - z) * nn + z * xo;
        hvA[jj] = fmaxf(v, 0.f);

        float rb = sigm(rBc[jj]);
        float zb = sigm(zBc[jj]);
        float nb_ = tanhfast(nBc[jj] + rb * hBc[jj]);
        float xob = tX[(n + 64) * NPAD + jl + jj];
        float vb = (1.f - zb) * nb_ + zb * xob;
        hvB[jj] = fmaxf(vb, 0.f);

        if (sout != nullptr) {
            float wav = dwa[jl + jj];
            float wbv = (mode == 0) ? dwb[jl + jj] : wav;
            float a1A = (mode == 1) ? 0.5f * (hvA[jj] + xo)  : hvA[jj];
            float a1B = (mode == 1) ? 0.5f * (hvB[jj] + xob) : hvB[jj];
            paA = fmaf(a1A, wav, paA); pbA = fmaf(hvA[jj], wbv, pbA);
            paB = fmaf(a1B, wav, paB); pbB = fmaf(hvB[jj], wbv, pbB);
        }
    }
    __syncthreads();          // all phase-C reads of tA/tX done
    #pragma unroll
    for (int jj = 0; jj < 8; ++jj) {
        tA[n * NPAD + jl + jj] = hvA[jj];
        tA[(n + 64) * NPAD + jl + jj] = hvB[jj];
    }
    if (sout != nullptr) {
        int w2i = (threadIdx.x >> 6) << 1;              // slot 0..14
        tX[n * 17 + w2i]            = paA;
        tX[n * 17 + w2i + 1]        = pbA;
        tX[(n + 64) * 17 + w2i]     = paB;
        tX[(n + 64) * 17 + w2i + 1] = pbB;
    }
    __syncthreads();
    for (int j = threadIdx.x; j < 2048; j += 512) {
        int r = j >> 4, c4 = (j & 15) << 2; int gr = r0 + r;
        if (gr < M) {
            int b = r * NPAD + c4;
            float4 ov = make_float4(tA[b], tA[b + 1], tA[b + 2], tA[b + 3]);
            *(float4*)(xout + (size_t)gr * 64 + c4) = ov;
        }
    }
    if (sout != nullptr && threadIdx.x < 128) {
        int r = threadIdx.x; int gr = r0 + r;
        if (gr < M) {
            float sa = 0.f, sb = 0.f;
            #pragma unroll
            for (int w = 0; w < 16; w += 2) { sa += tX[r * 17 + w]; sb += tX[r * 17 + w + 1]; }
            if (mode == 2) {
                sout[gr] = sa + dwb[0];
            } else {
                sout[gr] = sa; tout[gr] = sb;
            }
        }
    }
}

// ---------- readout: wave per graph, contiguous segment sum + relu ----------
__global__ __launch_bounds__(256) void k_seg_sum_relu(
    const float* __restrict__ x, const int* __restrict__ gst,
    float* __restrict__ outp, int G_)
{
    int g = (blockIdx.x * 256 + threadIdx.x) >> 6;
    int lane = threadIdx.x & 63;
    if (g >= G_) return;
    float S0 = 0.f, S1 = 0.f, S2 = 0.f, S3 = 0.f;
    int end = gst[g + 1];
    int i = gst[g];
    for (; i + 4 <= end; i += 4) {
        S0 += x[(size_t)i * 64 + lane];
        S1 += x[(size_t)(i + 1) * 64 + lane];
        S2 += x[(size_t)(i + 2) * 64 + lane];
        S3 += x[(size_t)(i + 3) * 64 + lane];
    }
    for (; i < end; ++i) S0 += x[(size_t)i * 64 + lane];
    outp[(size_t)g * 64 + lane] = fmaxf((S0 + S1) + (S2 + S3), 0.f);
}

// ---------- molecule attention: wave per graph, pipelined gather ----------
__global__ __launch_bounds__(256) void k_mol_gather(
    const float* __restrict__ xf, const float* __restrict__ cach,
    const float* __restrict__ stateIn, const int* __restrict__ gst,
    const float* __restrict__ dd,
    const float* __restrict__ maw, const float* __restrict__ mab,
    float* __restrict__ Agg, int G_)
{
    int g = (blockIdx.x * 256 + threadIdx.x) >> 6;
    int lane = threadIdx.x & 63;
    if (g >= G_) return;
    float o = stateIn[(size_t)g * 64 + lane];
    float og = wredsum(o * maw[lane]);
    float mb = mab[0];
    int beg = gst[g], end = gst[g + 1];
    float m = -INFINITY, d = 0.f, S = 0.f;
    for (int cs = beg; cs < end; cs += 64) {
        int cnt = min(64, end - cs);
        // issue first row-group loads before the score chain
        size_t rb = (size_t)cs * 64 + lane;
        float x0 = xf[rb],      c0 = cach[rb];
        float x1 = xf[rb + 64], c1 = cach[rb + 64];
        float x2 = xf[rb + 128], c2 = cach[rb + 128];
        float x3 = xf[rb + 192], c3 = cach[rb + 192];
        float sc_l = -INFINITY;
        if (lane < cnt) sc_l = leaky(og + dd[cs + lane] + mb);
        float cmax = wredmax(sc_l);
        float mn = fmaxf(m, cmax);
        float c = __expf(m - mn);
        float w_l = __expf(sc_l - mn);   // 0 for lanes >= cnt
        d = d * c + wredsum(w_l);
        S *= c;
        int cnt4 = (cnt + 3) & ~3;
        for (int l = 0; l < cnt4; l += 4) {
            int ln = (l + 4 < cnt4) ? l + 4 : 0;
            size_t rn = (size_t)(cs + ln) * 64 + lane;
            float y0 = xf[rn],       d0 = cach[rn];
            float y1 = xf[rn + 64],  d1 = cach[rn + 64];
            float y2 = xf[rn + 128], d2 = cach[rn + 128];
            float y3 = xf[rn + 192], d3 = cach[rn + 192];
            float w0 = bcastf(w_l, l),     w1 = bcastf(w_l, l + 1);
            float w2 = bcastf(w_l, l + 2), w3 = bcastf(w_l, l + 3);
            S = fmaf(w0, 0.5f * (x0 + c0), S);
            S = fmaf(w1, 0.5f * (x1 + c1), S);
            S = fmaf(w2, 0.5f * (x2 + c2), S);
            S = fmaf(w3, 0.5f * (x3 + c3), S);
            x0 = y0; c0 = d0; x1 = y1; c1 = d1;
            x2 = y2; c2 = d2; x3 = y3; c3 = d3;
        }
        m = mn;
    }
    Agg[(size_t)g * 64 + lane] = S / (d + 1e-16f);
}

// =====================================================================
extern "C" void kernel_launch(void* const* d_in, const int* in_sizes, int n_in,
                              void* d_out, int out_size, void* d_ws, size_t ws_size,
                              hipStream_t stream) {
    const float* raw           = (const float*)d_in[0];
    const int*   ei            = (const int*)d_in[1];
    const float* ea            = (const float*)d_in[2];
    const int*   batch         = (const int*)d_in[3];
    const float* lin1_w        = (const float*)d_in[4];
    const float* lin1_b        = (const float*)d_in[5];
    const float* gate_nl_w     = (const float*)d_in[6];
    const float* gate_nl_b     = (const float*)d_in[7];
    const float* gate_align_w  = (const float*)d_in[8];
    const float* gate_align_b  = (const float*)d_in[9];
    const float* gate_attend_w = (const float*)d_in[10];
    const float* gate_attend_b = (const float*)d_in[11];
    const float* conv_align_w  = (const float*)d_in[12];
    const float* conv_align_b  = (const float*)d_in[13];
    const float* conv_attend_w = (const float*)d_in[14];
    const float* conv_attend_b = (const float*)d_in[15];
    const float* gru_wih       = (const float*)d_in[16];
    const float* gru_whh       = (const float*)d_in[17];
    const float* gru_bih       = (const float*)d_in[18];
    const float* gru_bhh       = (const float*)d_in[19];
    const float* mol_align_w   = (const float*)d_in[20];
    const float* mol_align_b   = (const float*)d_in[21];
    const float* mol_attend_w  = (const float*)d_in[22];
    const float* mol_attend_b  = (const float*)d_in[23];
    const float* mol_wih       = (const float*)d_in[24];
    const float* mol_whh       = (const float*)d_in[25];
    const float* mol_bih       = (const float*)d_in[26];
    const float* mol_bhh       = (const float*)d_in[27];
    const float* lin2_w        = (const float*)d_in[28];
    const float* lin2_b        = (const float*)d_in[29];
    float* out = (float*)d_out;

    const int N = in_sizes[3];
    const int E = in_sizes[1] / 2;
    const int G = out_size;
    const size_t N64 = (size_t)N * 64;
    const size_t G64 = (size_t)G * 64;

    // ---- workspace layout ----
    float* f = (float*)d_ws;
    float* xA    = f;
    float* xB    = xA + N64;
    float* xD    = xB + N64;
    float* Agg   = xD + N64;
    float* u     = Agg + N64;
    float* sN    = u + N64;
    float* tN    = sN + N;
    float* dd    = tN + N;
    float* outS  = dd + N;
    float* outS2 = outS + G64;
    float* aggG  = outS2 + G64;
    int* row  = (int*)(aggG + G64);
    int* csrc = row + (N + 1);
    int* ceid = csrc + E;
    int* bsum = ceid + E;
    int* gst  = bsum + 512;
    int* deg = (int*)Agg;
    int* cur = deg + N;

    const int nb_node64  = (N + 63) / 64;
    const int nb_node128 = (N + 127) / 128;
    const int nb_edge   = (E + 255) / 256;
    const int nb_nodes  = (N + 255) / 256;
    const int nb_waveN  = (N + 3) / 4;
    const int nb_waveG  = (G + 3) / 4;
    const int nb_nodeG  = (G + 127) / 128;

    // ---- CSR build ----
    hipMemsetAsync(deg, 0, (size_t)N * 4, stream);
    k_hist<<<nb_edge, 256, 0, stream>>>(ei, deg, E);
    k_scan1<<<nb_nodes, 256, 0, stream>>>(deg, bsum, N);
    k_scan2<<<1, 512, 0, stream>>>(bsum, nb_nodes);
    k_scan3<<<nb_nodes, 256, 0, stream>>>(deg, bsum, row, cur, N, E);
    k_scatter<<<nb_edge, 256, 0, stream>>>(ei, cur, csrc, ceid, E);
    k_gbounds<<<nb_nodes, 256, 0, stream>>>(batch, gst, N, G);

    // ---- lin1 (+fused gate align dot -> sN) + gate node-part precompute ----
    k_dense64<<<nb_node64, 256, 0, stream>>>(raw, lin1_w, 64, lin1_b, xA, N, 1,
                                             gate_align_w, sN);
    k_dense64<<<nb_node64, 256, 0, stream>>>(raw, gate_nl_w, 80, gate_nl_b, u, N, 0,
                                             nullptr, nullptr);

    // ---- layer 0: GATEConv (xA -> xB); emits align dots for GAT layer 0 ----
    k_gate_gather<<<nb_waveN, 256, 0, stream>>>(u, ea, row, csrc, ceid,
                                                gate_nl_w, gate_align_w, gate_align_b,
                                                sN, Agg, N);
    k_node_update<<<nb_node128, 512, 0, stream>>>(Agg, xA, gate_attend_w, gate_attend_b,
                                                  gru_wih, gru_whh, gru_bih, gru_bhh, xB, N,
                                                  conv_align_w, conv_align_w + 64, sN, tN, 0);

    // ---- GAT layer 0 (xB -> xD); emits align dots for GAT layer 1 ----
    k_gat_gather<<<nb_waveN, 256, 0, stream>>>(row, csrc, xB, sN, tN, conv_align_b, Agg, N);
    k_node_update<<<nb_node128, 512, 0, stream>>>(Agg, xB, conv_attend_w, conv_attend_b,
                                                  gru_wih + 12288, gru_whh + 12288,
                                                  gru_bih + 192, gru_bhh + 192, xD, N,
                                                  conv_align_w + 128, conv_align_w + 192, sN, tN, 0);

    // ---- GAT layer 1 (xD -> xA); emits mol dots dd0 -> dd, dd1 -> tN ----
    k_gat_gather<<<nb_waveN, 256, 0, stream>>>(row, csrc, xD, sN, tN, conv_align_b + 1, Agg, N);
    k_node_update<<<nb_node128, 512, 0, stream>>>(Agg, xD, conv_attend_w + 4096, conv_attend_b + 64,
                                                  gru_wih + 24576, gru_whh + 24576,
                                                  gru_bih + 384, gru_bhh + 384, xA, N,
                                                  mol_align_w + 64, mol_align_w + 64, dd, tN, 1);

    // ---- molecule readout ----
    k_seg_sum_relu<<<nb_waveG, 256, 0, stream>>>(xA, gst, outS, G);

    // t=0: cached = xD, dots = dd (0.5(xA+xD).maw2)
    k_mol_gather<<<nb_waveG, 256, 0, stream>>>(xA, xD, outS, gst, dd,
                                               mol_align_w, mol_align_b, aggG, G);
    k_node_update<<<nb_nodeG, 512, 0, stream>>>(aggG, outS, mol_attend_w, mol_attend_b,
                                                mol_wih, mol_whh, mol_bih, mol_bhh, outS2, G,
                                                nullptr, nullptr, nullptr, nullptr, 0);
    // t=1: cached = xA, dots = tN (xA.maw2); fused lin2 -> out
    k_mol_gather<<<nb_waveG, 256, 0, stream>>>(xA, xA, outS2, gst, tN,
                                               mol_align_w, mol_align_b, aggG, G);
    k_node_update<<<nb_nodeG, 512, 0, stream>>>(aggG, outS2, mol_attend_w, mol_attend_b,
                                                mol_wih, mol_whh, mol_bih, mol_bhh, outS, G,
                                                lin2_w, lin2_b, out, nullptr, 2);
}